// Round 6
// baseline (166.844 us; speedup 1.0000x reference)
//
#include <hip/hip_runtime.h>
#include <cmath>

#define NN 50000
#define NE 800000
#define INC 128
#define C1 256
#define O2 64
#define NG 64
#define NSLOT 64      // pooling atomic slots
#define NBKT 196      // CSR sort buckets: 256 dsts each
#define CHUNK 2048    // edges per binA block
#define NBA ((NE + CHUNK - 1) / CHUNK)   // 391 binA sort blocks
#define SUMW (NSLOT * NG * O2)           // 262144 words
#define SUMQ (SUMW / 4)                  // 65536 quads -> 256 blocks
#define PB_HB 256     // histogram blocks in prep
#define EPB (NE / PB_HB)  // 3125 edges per hist block (exact)
#define PB_W 193      // W-transpose + bounds blocks

typedef short bf16x8 __attribute__((ext_vector_type(8)));
typedef float f32x4 __attribute__((ext_vector_type(4)));
typedef float f32x2 __attribute__((ext_vector_type(2)));

__device__ __forceinline__ float lrelu02(float x) { return x >= 0.f ? x : 0.2f * x; }
__device__ __forceinline__ float eluf(float x) { return x > 0.f ? x : expm1f(x); }
__device__ __forceinline__ unsigned short f2bf(float f) {
    unsigned u = __float_as_uint(f);
    u += 0x7fffu + ((u >> 16) & 1u);
    return (unsigned short)(u >> 16);
}
__device__ __forceinline__ float bf2f(unsigned short s) {
    return __uint_as_float(((unsigned)s) << 16);
}

// ---- fp8 e4m3 encode/decode (HW converts on gfx950; SW fallback) ----
__device__ __forceinline__ unsigned char f2fp8(float f) {
#if __has_builtin(__builtin_amdgcn_cvt_pk_fp8_f32)
    return (unsigned char)(__builtin_amdgcn_cvt_pk_fp8_f32(f, f, 0, false) & 0xff);
#else
    unsigned u = __float_as_uint(f);
    unsigned s = u >> 31;
    float a = fabsf(f);
    int e = ((u >> 23) & 255) - 127;
    if (e < -6) {
        int q = (int)rintf(ldexpf(a, 9));
        return (unsigned char)((s << 7) | (unsigned)q);
    }
    unsigned m = u & 0x7fffffu;
    const unsigned keep = 20;
    unsigned mr = m + ((1u << (keep - 1)) - 1 + ((m >> keep) & 1));
    if (mr >> 23) { e += 1; mr = 0; }
    unsigned m3 = (mr >> keep) & 7;
    if (e > 8) { e = 8; m3 = 6; }
    return (unsigned char)((s << 7) | ((unsigned)(e + 7) << 3) | m3);
#endif
}
__device__ __forceinline__ float fp81(unsigned b) {
#if __has_builtin(__builtin_amdgcn_cvt_f32_fp8)
    return __builtin_amdgcn_cvt_f32_fp8((int)b, 0);
#else
    unsigned s = (b >> 7) & 1, e = (b >> 3) & 15, m = b & 7;
    float v = (e == 0) ? ldexpf((float)m, -9) : ldexpf((float)(8 + m), (int)e - 10);
    return s ? -v : v;
#endif
}
__device__ __forceinline__ float4 fp8x4(unsigned uu) {
#if __has_builtin(__builtin_amdgcn_cvt_pk_f32_fp8)
    f32x2 lo = __builtin_amdgcn_cvt_pk_f32_fp8(uu, false);
    f32x2 hi = __builtin_amdgcn_cvt_pk_f32_fp8(uu, true);
    return make_float4(lo[0], lo[1], hi[0], hi[1]);
#else
    return make_float4(fp81(uu & 255), fp81((uu >> 8) & 255),
                       fp81((uu >> 16) & 255), fp81(uu >> 24));
#endif
}

// ---- zero bh|gcur (512 words = 128 quads, one block) ----
__global__ __launch_bounds__(128) void gat_zero(float4* __restrict__ z) {
    z[threadIdx.x] = make_float4(0.f, 0.f, 0.f, 0.f);
}

// ---- fused prep: [0,256) bucket histogram (196 buckets) | [256,449) W transpose + bounds ----
__global__ __launch_bounds__(256) void gat_prep(const int* __restrict__ ei,
                                                const float* __restrict__ W1,
                                                const float* __restrict__ W2,
                                                const int* __restrict__ batch,
                                                int* __restrict__ bh,
                                                unsigned short* __restrict__ w1t,
                                                unsigned short* __restrict__ w2t,
                                                int* __restrict__ bnds) {
    int b = blockIdx.x, t = threadIdx.x;
    if (b < PB_HB) {
        __shared__ int h[256];
        h[t] = 0;
        __syncthreads();
        int j0 = b * EPB;
        for (int k = t; k < EPB; k += 256)
            atomicAdd(&h[ei[NE + j0 + k] >> 8], 1);
        __syncthreads();
        if (t < NBKT && h[t] > 0) atomicAdd(bh + t, h[t]);
    } else {
        int bb_ = b - PB_HB;
        if (bb_ < 128) {                     // w1t[256][128] = W1^T
            int idx = bb_ * 256 + t;
            int n = idx >> 7, k = idx & 127;
            w1t[idx] = f2bf(W1[(size_t)k * C1 + n]);
        } else if (bb_ < 192) {              // w2t[64][256] = W2^T
            int idx = (bb_ - 128) * 256 + t;
            int n = idx >> 8, k = idx & 255;
            w2t[idx] = f2bf(W2[(size_t)k * O2 + n]);
        } else {
            if (t <= NG) {
                int lo = 0, hi = NN;
                while (lo < hi) {
                    int mid = (lo + hi) >> 1;
                    if (batch[mid] < t) lo = mid + 1; else hi = mid;
                }
                bnds[t] = lo;
            }
        }
    }
}

// ---- scan of 196 bucket counts -> bucket bases bb[0..196] ----
__global__ __launch_bounds__(256) void gat_scanb(const int* __restrict__ bh,
                                                 int* __restrict__ bb) {
    __shared__ int lds[256];
    int t = threadIdx.x;
    int v = (t < NBKT) ? bh[t] : 0;
    lds[t] = v;
    __syncthreads();
#pragma unroll
    for (int o = 1; o < 256; o <<= 1) {
        int add = (t >= o) ? lds[t - o] : 0;
        __syncthreads();
        lds[t] += add;
        __syncthreads();
    }
    if (t <= NBKT) bb[t] = lds[t] - v;   // exclusive; bb[196] = NE
}

// ---- CSR build phase A: counting sort by bucket; extra blocks zero `sums` ----
__global__ __launch_bounds__(256) void gat_binA(const int* __restrict__ ei,
                                                const int* __restrict__ bb,
                                                int* __restrict__ gcur,
                                                unsigned* __restrict__ ebuf,
                                                float4* __restrict__ sumsq) {
    __shared__ int hist[256], lofs[256], gofs[256], fill[256];
    __shared__ unsigned stage[CHUNK];
    const int t = threadIdx.x;
    if (blockIdx.x >= NBA) {                 // sums-zero blocks (overlapped with sort)
        int i = (blockIdx.x - NBA) * 256 + t;
        sumsq[i] = make_float4(0.f, 0.f, 0.f, 0.f);
        return;
    }
    const int j0 = blockIdx.x * CHUNK;
    const int n = min(CHUNK, NE - j0);
    hist[t] = 0;
    __syncthreads();
    for (int k = t; k < n; k += 256)
        atomicAdd(&hist[ei[NE + j0 + k] >> 8], 1);
    __syncthreads();
    int v = hist[t];
    lofs[t] = v;
    __syncthreads();
#pragma unroll
    for (int o = 1; o < 256; o <<= 1) {
        int add = (t >= o) ? lofs[t - o] : 0;
        __syncthreads();
        lofs[t] += add;
        __syncthreads();
    }
    int excl = lofs[t] - v;
    __syncthreads();
    lofs[t] = excl;
    if (t < NBKT && v > 0)
        gofs[t] = bb[t] + atomicAdd(gcur + t, v);
    fill[t] = 0;
    __syncthreads();
    for (int k = t; k < n; k += 256) {
        int j = j0 + k;
        int d = ei[NE + j];
        int s = ei[j];
        int b = d >> 8;
        int r = atomicAdd(&fill[b], 1);
        stage[lofs[b] + r] = (unsigned)s | ((unsigned)(d & 255) << 16) | ((unsigned)b << 24);
    }
    __syncthreads();
    for (int idx = t; idx < n; idx += 256) {
        unsigned u = stage[idx];
        int b = u >> 24;
        ebuf[gofs[b] + (idx - lofs[b])] = u;
    }
}

// ---- merged launch: blocks [0,NBKT) = binB (per-dst rowptr + placement of the
//      FULL packed word (s|dl|bkt) into csru); blocks [NBKT, ...) = gemm1 ----
__global__ __launch_bounds__(256) void gat_binB_gemm1(
        const unsigned* __restrict__ ebuf, const int* __restrict__ bb,
        int* __restrict__ rowptr, unsigned* __restrict__ csru,
        const float* __restrict__ x, const unsigned short* __restrict__ w1t,
        const float* __restrict__ as1, const float* __restrict__ ad1,
        unsigned char* __restrict__ h1f8, float* __restrict__ aS,
        float* __restrict__ aD) {
    __shared__ unsigned short As[64][136];
    __shared__ unsigned short Bh[64][136];
    __shared__ int cntB[256];
    __shared__ int scB[256];
    const int tid = threadIdx.x;
    if (blockIdx.x < NBKT) {
        const int b = blockIdx.x, t = tid;
        const int base = bb[b], end = bb[b + 1];
        cntB[t] = 0;
        __syncthreads();
        for (int idx = base + t; idx < end; idx += 256)
            atomicAdd(&cntB[(ebuf[idx] >> 16) & 255], 1);
        __syncthreads();
        int v = cntB[t];
        scB[t] = v;
        __syncthreads();
#pragma unroll
        for (int o = 1; o < 256; o <<= 1) {
            int add = (t >= o) ? scB[t - o] : 0;
            __syncthreads();
            scB[t] += add;
            __syncthreads();
        }
        int rp = base + scB[t] - v;      // global CSR start for dst (b<<8)+t
        __syncthreads();
        scB[t] = rp;
        int d = (b << 8) + t;
        if (d < NN) rowptr[d] = rp;
        if (b == 0 && t == 0) rowptr[NN] = NE;
        cntB[t] = 0;
        __syncthreads();
        for (int idx = base + t; idx < end; idx += 256) {
            unsigned u = ebuf[idx];
            int dl = (u >> 16) & 255;
            int r = atomicAdd(&cntB[dl], 1);
            csru[scB[dl] + r] = u;       // keep full (s | dl<<16 | bkt<<24)
        }
        return;
    }
    const int m0 = (blockIdx.x - NBKT) * 64;
    const int seg = tid & 15, r = tid >> 4;
#pragma unroll
    for (int i = 0; i < 4; ++i) {
        int rr = r + i * 16, gr = m0 + rr;
        ushort4 o0 = {0, 0, 0, 0}, o1 = {0, 0, 0, 0};
        if (gr < NN) {
            const float* p = x + (size_t)gr * INC + seg * 8;
            float4 v0 = *(const float4*)p;
            float4 v1 = *(const float4*)(p + 4);
            o0.x = f2bf(v0.x); o0.y = f2bf(v0.y); o0.z = f2bf(v0.z); o0.w = f2bf(v0.w);
            o1.x = f2bf(v1.x); o1.y = f2bf(v1.y); o1.z = f2bf(v1.z); o1.w = f2bf(v1.w);
        }
        *(ushort4*)&As[rr][seg * 8] = o0;
        *(ushort4*)&As[rr][seg * 8 + 4] = o1;
    }
    __syncthreads();
    const int lane = tid & 63, w = tid >> 6;
    const int lr = lane & 15, lk = (lane >> 4) * 8;
    bf16x8 a[4];
#pragma unroll
    for (int q = 0; q < 4; ++q)
        a[q] = *(const bf16x8*)&As[w * 16 + lr][q * 32 + lk];
    const int rbase = m0 + w * 16 + (lane >> 4) * 4;
    float psH[2][4] = {}, pdH[2][4] = {};
    for (int it = 0; it < 4; ++it) {
        const int n0 = it * 64;
        if (it > 0) __syncthreads();
        {
#pragma unroll
            for (int i = 0; i < 4; ++i) {
                int nr = r + i * 16;
                *(int4*)&Bh[nr][seg * 8] = *(const int4*)(w1t + (size_t)(n0 + nr) * INC + seg * 8);
            }
        }
        __syncthreads();
        f32x4 acc[4] = {};
#pragma unroll
        for (int j = 0; j < 4; ++j) {
#pragma unroll
            for (int q = 0; q < 4; ++q) {
                bf16x8 bh = *(const bf16x8*)&Bh[j * 16 + lr][q * 32 + lk];
                acc[j] = __builtin_amdgcn_mfma_f32_16x16x32_bf16(a[q], bh, acc[j], 0, 0, 0);
            }
        }
#pragma unroll
        for (int j = 0; j < 4; ++j) {
            int col = n0 + j * 16 + lr;
#pragma unroll
            for (int r4 = 0; r4 < 4; ++r4) {
                int gr = rbase + r4;
                if (gr < NN) h1f8[(size_t)gr * C1 + col] = f2fp8(acc[j][r4]);
            }
        }
        const int head = n0 >> 7;
        float attS[4], attD[4];
#pragma unroll
        for (int j = 0; j < 4; ++j) {
            attS[j] = as1[n0 + j * 16 + lr];
            attD[j] = ad1[n0 + j * 16 + lr];
        }
#pragma unroll
        for (int r4 = 0; r4 < 4; ++r4) {
#pragma unroll
            for (int j = 0; j < 4; ++j) {
                psH[head][r4] = fmaf(acc[j][r4], attS[j], psH[head][r4]);
                pdH[head][r4] = fmaf(acc[j][r4], attD[j], pdH[head][r4]);
            }
        }
    }
#pragma unroll
    for (int r4 = 0; r4 < 4; ++r4) {
        float p0 = psH[0][r4], p1 = psH[1][r4];
        float d0 = pdH[0][r4], d1 = pdH[1][r4];
#pragma unroll
        for (int o = 1; o < 16; o <<= 1) {
            p0 += __shfl_xor(p0, o, 64);
            p1 += __shfl_xor(p1, o, 64);
            d0 += __shfl_xor(d0, o, 64);
            d1 += __shfl_xor(d1, o, 64);
        }
        if (lr == 0) {
            int gr = rbase + r4;
            if (gr < NN) {
                *(float2*)(aS + (size_t)gr * 2) = make_float2(p0, p1);
                *(float2*)(aD + (size_t)gr * 2) = make_float2(d0, d1);
            }
        }
    }
}

// ---- streaming per-edge records, layer 1, split per head:
//      eb[h*NE + j] = {e_h, s*256 (byte offset)} ----
__global__ __launch_bounds__(256) void gat_e1(const unsigned* __restrict__ csru,
                                              const float2* __restrict__ aS,
                                              const float2* __restrict__ aD,
                                              float2* __restrict__ eb) {
    int j = blockIdx.x * 256 + threadIdx.x;
    unsigned u = csru[j];
    unsigned s = u & 0xffffu;
    int d = (int)((u >> 24) << 8) | (int)((u >> 16) & 255u);
    float2 as_ = aS[s];
    float2 ad_ = aD[d];
    float off = __uint_as_float(s << 8);
    eb[j]      = make_float2(__expf(lrelu02(as_.x + ad_.x)), off);
    eb[NE + j] = make_float2(__expf(lrelu02(as_.y + ad_.y)), off);
}

// ---- streaming per-edge record, layer 2: {e, s*64 (byte offset)} ----
__global__ __launch_bounds__(256) void gat_e2(const unsigned* __restrict__ csru,
                                              const float* __restrict__ aS,
                                              const float* __restrict__ aD,
                                              float2* __restrict__ eb) {
    int j = blockIdx.x * 256 + threadIdx.x;
    unsigned u = csru[j];
    unsigned s = u & 0xffffu;
    int d = (int)((u >> 24) << 8) | (int)((u >> 16) & 255u);
    eb[j] = make_float2(__expf(lrelu02(aS[s] + aD[d])),
                        __uint_as_float(s << 6));
}

// --- GEMM2 (MFMA) + fused att2 (full row per block, direct store); h2 out fp8 ---
__global__ __launch_bounds__(256) void gat_gemm2(const unsigned short* __restrict__ out1b,
                                                 const float* __restrict__ b1,
                                                 const unsigned short* __restrict__ w2t,
                                                 const float* __restrict__ as2,
                                                 const float* __restrict__ ad2,
                                                 unsigned char* __restrict__ h2f8,
                                                 float* __restrict__ aS,
                                                 float* __restrict__ aD) {
    __shared__ unsigned short As[64][136];
    __shared__ unsigned short Bh[64][136];
    const int m0 = blockIdx.x * 64;
    const int tid = threadIdx.x;
    const int lane = tid & 63, w = tid >> 6;
    const int lr = lane & 15, lk = (lane >> 4) * 8;
    f32x4 acc[4] = {};
    for (int kc = 0; kc < 2; ++kc) {
        __syncthreads();
        {
            int seg = tid & 15, r = tid >> 4;
            float4 bia0 = *(const float4*)(b1 + kc * 128 + seg * 8);
            float4 bia1 = *(const float4*)(b1 + kc * 128 + seg * 8 + 4);
#pragma unroll
            for (int i = 0; i < 4; ++i) {
                int rr = r + i * 16, gr = m0 + rr;
                ushort4 o0 = {0, 0, 0, 0}, o1 = {0, 0, 0, 0};
                if (gr < NN) {
                    const unsigned short* p = out1b + (size_t)gr * C1 + kc * 128 + seg * 8;
                    ushort4 u0 = *(const ushort4*)p;
                    ushort4 u1 = *(const ushort4*)(p + 4);
                    o0.x = f2bf(eluf(bf2f(u0.x) + bia0.x));
                    o0.y = f2bf(eluf(bf2f(u0.y) + bia0.y));
                    o0.z = f2bf(eluf(bf2f(u0.z) + bia0.z));
                    o0.w = f2bf(eluf(bf2f(u0.w) + bia0.w));
                    o1.x = f2bf(eluf(bf2f(u1.x) + bia1.x));
                    o1.y = f2bf(eluf(bf2f(u1.y) + bia1.y));
                    o1.z = f2bf(eluf(bf2f(u1.z) + bia1.z));
                    o1.w = f2bf(eluf(bf2f(u1.w) + bia1.w));
                }
                *(ushort4*)&As[rr][seg * 8] = o0;
                *(ushort4*)&As[rr][seg * 8 + 4] = o1;
            }
#pragma unroll
            for (int i = 0; i < 4; ++i) {
                int nr = r + i * 16;
                *(int4*)&Bh[nr][seg * 8] = *(const int4*)(w2t + (size_t)nr * C1 + kc * 128 + seg * 8);
            }
        }
        __syncthreads();
        bf16x8 a[4];
#pragma unroll
        for (int q = 0; q < 4; ++q)
            a[q] = *(const bf16x8*)&As[w * 16 + lr][q * 32 + lk];
#pragma unroll
        for (int j = 0; j < 4; ++j) {
#pragma unroll
            for (int q = 0; q < 4; ++q) {
                bf16x8 bh = *(const bf16x8*)&Bh[j * 16 + lr][q * 32 + lk];
                acc[j] = __builtin_amdgcn_mfma_f32_16x16x32_bf16(a[q], bh, acc[j], 0, 0, 0);
            }
        }
    }
    const int rbase = m0 + w * 16 + (lane >> 4) * 4;
#pragma unroll
    for (int j = 0; j < 4; ++j) {
        int col = j * 16 + lr;
#pragma unroll
        for (int r4 = 0; r4 < 4; ++r4) {
            int gr = rbase + r4;
            if (gr < NN) h2f8[(size_t)gr * O2 + col] = f2fp8(acc[j][r4]);
        }
    }
    float attS[4], attD[4];
#pragma unroll
    for (int j = 0; j < 4; ++j) {
        attS[j] = as2[j * 16 + lr];
        attD[j] = ad2[j * 16 + lr];
    }
#pragma unroll
    for (int r4 = 0; r4 < 4; ++r4) {
        float ps = 0.f, pd = 0.f;
#pragma unroll
        for (int j = 0; j < 4; ++j) {
            ps = fmaf(acc[j][r4], attS[j], ps);
            pd = fmaf(acc[j][r4], attD[j], pd);
        }
#pragma unroll
        for (int o = 1; o < 16; o <<= 1) {
            ps += __shfl_xor(ps, o, 64);
            pd += __shfl_xor(pd, o, 64);
        }
        if (lr == 0) {
            int gr = rbase + r4;
            if (gr < NN) { aS[gr] = ps; aD[gr] = pd; }
        }
    }
}

// ------- aggregation layer 1: 1 dst/WAVE. The wave's two 32-lane groups take
//         even/odd edges of the SAME dst (shared st/en -> zero divergence);
//         16 edges in flight per wave, typical trip count 1. Lane = 8 fp8 ch;
//         head picked by per-lane record base (no select). Packed v_pk_fma_f32
//         accumulate. Cross-group combine: 9 shfl_xor once per dst. -------
__global__ __launch_bounds__(256) void gat_agg1(const int* __restrict__ rowptr,
                                                const float2* __restrict__ eb1,
                                                const unsigned char* __restrict__ h1f8,
                                                unsigned short* __restrict__ out1b) {
    const int wid = threadIdx.x >> 6, lane = threadIdx.x & 63;
    const int grp = lane >> 5, li = lane & 31;
    const int d = blockIdx.x * 4 + wid;    // 12500 blocks * 4 = 50000 exact
    const int st = rowptr[d], en = rowptr[d + 1];
    const int coff = li << 3;              // 8 fp8 channels per lane (byte offset)
    const float2* eb = eb1 + ((li >= 16) ? NE : 0);   // head base per lane
    f32x2 A0 = {0.f, 0.f}, A1 = {0.f, 0.f}, A2 = {0.f, 0.f}, A3 = {0.f, 0.f};
    float sd = 0.f;
    const int en1 = en - 1;
    for (int i = st + grp; i < en; i += 16) {
        float2 q[8]; uint2 v[8];
#pragma unroll
        for (int k = 0; k < 8; ++k) {
            int j = i + 2 * k;
            int jc = min(j, en1);
            float2 qq = eb[jc];
            v[k] = *(const uint2*)(h1f8 + (size_t)__float_as_uint(qq.y) + coff);
            qq.x = (j <= en1) ? qq.x : 0.f;
            q[k] = qq;
        }
#pragma unroll
        for (int k = 0; k < 8; ++k) {
            float m = q[k].x;
            sd += m;
#if __has_builtin(__builtin_amdgcn_cvt_pk_f32_fp8)
            f32x2 mm = {m, m};
            A0 += __builtin_amdgcn_cvt_pk_f32_fp8(v[k].x, false) * mm;
            A1 += __builtin_amdgcn_cvt_pk_f32_fp8(v[k].x, true)  * mm;
            A2 += __builtin_amdgcn_cvt_pk_f32_fp8(v[k].y, false) * mm;
            A3 += __builtin_amdgcn_cvt_pk_f32_fp8(v[k].y, true)  * mm;
#else
            float4 w0 = fp8x4(v[k].x), w1 = fp8x4(v[k].y);
            A0[0] = fmaf(w0.x, m, A0[0]); A0[1] = fmaf(w0.y, m, A0[1]);
            A1[0] = fmaf(w0.z, m, A1[0]); A1[1] = fmaf(w0.w, m, A1[1]);
            A2[0] = fmaf(w1.x, m, A2[0]); A2[1] = fmaf(w1.y, m, A2[1]);
            A3[0] = fmaf(w1.z, m, A3[0]); A3[1] = fmaf(w1.w, m, A3[1]);
#endif
        }
    }
    // combine the two edge-parity groups (lane ^ 32 has same channels/head)
    sd    += __shfl_xor(sd, 32, 64);
    A0[0] += __shfl_xor(A0[0], 32, 64); A0[1] += __shfl_xor(A0[1], 32, 64);
    A1[0] += __shfl_xor(A1[0], 32, 64); A1[1] += __shfl_xor(A1[1], 32, 64);
    A2[0] += __shfl_xor(A2[0], 32, 64); A2[1] += __shfl_xor(A2[1], 32, 64);
    A3[0] += __shfl_xor(A3[0], 32, 64); A3[1] += __shfl_xor(A3[1], 32, 64);
    float inv = 1.f / (sd + 1e-16f);
    ushort4 o;
    if (grp == 0) {                        // channels coff .. coff+3
        o.x = f2bf(A0[0] * inv); o.y = f2bf(A0[1] * inv);
        o.z = f2bf(A1[0] * inv); o.w = f2bf(A1[1] * inv);
        *(ushort4*)(out1b + (size_t)d * C1 + coff) = o;
    } else {                               // channels coff+4 .. coff+7
        o.x = f2bf(A2[0] * inv); o.y = f2bf(A2[1] * inv);
        o.z = f2bf(A3[0] * inv); o.w = f2bf(A3[1] * inv);
        *(ushort4*)(out1b + (size_t)d * C1 + coff + 4) = o;
    }
}

// ------- aggregation layer 2: 1 dst/WAVE, 4 edge-quadrants x 16 channel-lanes,
//         self-contained records, 16 edges in flight; packed pk_fma accumulate;
//         2 shfl_xor reductions; pooling merges 4 dsts -> 1 atomic/channel. -------
__global__ __launch_bounds__(256) void gat_agg2(const int* __restrict__ rowptr,
                                                const float2* __restrict__ eb2,
                                                const unsigned char* __restrict__ h2f8,
                                                const int* __restrict__ batch,
                                                const float* __restrict__ b2,
                                                float* __restrict__ sums) {
    __shared__ float pool[4][64];
    const int wid = threadIdx.x >> 6, lane = threadIdx.x & 63;
    const int eq = lane >> 4;              // edge quadrant 0..3
    const int li = lane & 15;              // channel lane
    const int c = li << 2;                 // 4 channels per lane (byte offset)
    const int d = blockIdx.x * 4 + wid;    // 12500 blocks * 4 = 50000 exact
    const int st = rowptr[d], en = rowptr[d + 1];
    f32x2 B0 = {0.f, 0.f}, B1 = {0.f, 0.f};
    float sd = 0.f;
    const int en1 = en - 1;
    for (int i = st; i < en; i += 16) {
        int j0 = i + eq, j1 = j0 + 4, j2 = j0 + 8, j3 = j0 + 12;
        int c0 = min(j0, en1), c1 = min(j1, en1), c2 = min(j2, en1), c3 = min(j3, en1);
        float2 q0 = eb2[c0], q1 = eb2[c1], q2 = eb2[c2], q3 = eb2[c3];
        unsigned v0 = *(const unsigned*)(h2f8 + (size_t)__float_as_uint(q0.y) + c);
        unsigned v1 = *(const unsigned*)(h2f8 + (size_t)__float_as_uint(q1.y) + c);
        unsigned v2 = *(const unsigned*)(h2f8 + (size_t)__float_as_uint(q2.y) + c);
        unsigned v3 = *(const unsigned*)(h2f8 + (size_t)__float_as_uint(q3.y) + c);
        float m0 = (j0 <= en1) ? q0.x : 0.f;
        float m1 = (j1 <= en1) ? q1.x : 0.f;
        float m2 = (j2 <= en1) ? q2.x : 0.f;
        float m3 = (j3 <= en1) ? q3.x : 0.f;
        sd += (m0 + m1) + (m2 + m3);
#if __has_builtin(__builtin_amdgcn_cvt_pk_f32_fp8)
        f32x2 mm0 = {m0, m0}, mm1 = {m1, m1}, mm2 = {m2, m2}, mm3 = {m3, m3};
        B0 += __builtin_amdgcn_cvt_pk_f32_fp8(v0, false) * mm0;
        B1 += __builtin_amdgcn_cvt_pk_f32_fp8(v0, true)  * mm0;
        B0 += __builtin_amdgcn_cvt_pk_f32_fp8(v1, false) * mm1;
        B1 += __builtin_amdgcn_cvt_pk_f32_fp8(v1, true)  * mm1;
        B0 += __builtin_amdgcn_cvt_pk_f32_fp8(v2, false) * mm2;
        B1 += __builtin_amdgcn_cvt_pk_f32_fp8(v2, true)  * mm2;
        B0 += __builtin_amdgcn_cvt_pk_f32_fp8(v3, false) * mm3;
        B1 += __builtin_amdgcn_cvt_pk_f32_fp8(v3, true)  * mm3;
#else
        float4 w;
        w = fp8x4(v0);
        B0[0] = fmaf(w.x, m0, B0[0]); B0[1] = fmaf(w.y, m0, B0[1]);
        B1[0] = fmaf(w.z, m0, B1[0]); B1[1] = fmaf(w.w, m0, B1[1]);
        w = fp8x4(v1);
        B0[0] = fmaf(w.x, m1, B0[0]); B0[1] = fmaf(w.y, m1, B0[1]);
        B1[0] = fmaf(w.z, m1, B1[0]); B1[1] = fmaf(w.w, m1, B1[1]);
        w = fp8x4(v2);
        B0[0] = fmaf(w.x, m2, B0[0]); B0[1] = fmaf(w.y, m2, B0[1]);
        B1[0] = fmaf(w.z, m2, B1[0]); B1[1] = fmaf(w.w, m2, B1[1]);
        w = fp8x4(v3);
        B0[0] = fmaf(w.x, m3, B0[0]); B0[1] = fmaf(w.y, m3, B0[1]);
        B1[0] = fmaf(w.z, m3, B1[0]); B1[1] = fmaf(w.w, m3, B1[1]);
#endif
    }
    float a0 = B0[0], a1 = B0[1], a2 = B1[0], a3 = B1[1];
    // reduce over the 4 edge-quadrants (lanes ^16, ^32 share channels)
    a0 += __shfl_xor(a0, 16, 64); a0 += __shfl_xor(a0, 32, 64);
    a1 += __shfl_xor(a1, 16, 64); a1 += __shfl_xor(a1, 32, 64);
    a2 += __shfl_xor(a2, 16, 64); a2 += __shfl_xor(a2, 32, 64);
    a3 += __shfl_xor(a3, 16, 64); a3 += __shfl_xor(a3, 32, 64);
    sd += __shfl_xor(sd, 16, 64); sd += __shfl_xor(sd, 32, 64);
    float inv = 1.f / (sd + 1e-16f);
    if (eq == 0)
        *(float4*)&pool[wid][c] = make_float4(a0 * inv, a1 * inv, a2 * inv, a3 * inv);
    __syncthreads();
    const int slot = blockIdx.x & (NSLOT - 1);
    const int d0 = blockIdx.x * 4;
    int g0 = batch[d0], g3 = batch[d0 + 3];
    if (g0 == g3) {                        // common case (sorted batch): 1 atomic/channel
        if (threadIdx.x < 64) {
            int ch = threadIdx.x;
            float bb_ = b2[ch];
            float v = 0.f;
#pragma unroll
            for (int r = 0; r < 4; ++r) {
                float t = pool[r][ch] + bb_;
                v += (t > 0.f) ? t : expm1f(t);
            }
            unsafeAtomicAdd(sums + ((size_t)slot * NG + g0) * O2 + ch, v);
        }
    } else {                               // graph boundary inside block (rare)
        int r = threadIdx.x >> 6, ch = threadIdx.x & 63;
        float t = pool[r][ch] + b2[ch];
        t = (t > 0.f) ? t : expm1f(t);
        unsafeAtomicAdd(sums + ((size_t)slot * NG + batch[d0 + r]) * O2 + ch, t);
    }
}

// ------- classifier: reduce slots, mean, @Wc + bc -------
__global__ __launch_bounds__(64) void gat_cls(const float* __restrict__ sums,
                                              const int* __restrict__ bnds,
                                              const float* __restrict__ Wc,
                                              const float* __restrict__ bc,
                                              float* __restrict__ out) {
    int g = blockIdx.x, c = threadIdx.x;
    float s = 0.f;
#pragma unroll
    for (int sl = 0; sl < NSLOT; ++sl)
        s += sums[((size_t)sl * NG + g) * O2 + c];
    float cnt = (float)(bnds[g + 1] - bnds[g]);
    float p = s / fmaxf(cnt, 1.f);
    float p0 = p * Wc[c * 2 + 0];
    float p1 = p * Wc[c * 2 + 1];
#pragma unroll
    for (int off = 1; off < 64; off <<= 1) {
        p0 += __shfl_xor(p0, off, 64);
        p1 += __shfl_xor(p1, off, 64);
    }
    if (c == 0) {
        out[g * 2 + 0] = p0 + bc[0];
        out[g * 2 + 1] = p1 + bc[1];
    }
}

extern "C" void kernel_launch(void* const* d_in, const int* in_sizes, int n_in,
                              void* d_out, int out_size, void* d_ws, size_t ws_size,
                              hipStream_t stream) {
    const float* x   = (const float*)d_in[0];
    const int*   ei  = (const int*)d_in[1];
    const int*   bat = (const int*)d_in[2];
    const float* W1  = (const float*)d_in[3];
    const float* as1 = (const float*)d_in[4];
    const float* ad1 = (const float*)d_in[5];
    const float* b1  = (const float*)d_in[6];
    const float* W2  = (const float*)d_in[7];
    const float* as2 = (const float*)d_in[8];
    const float* ad2 = (const float*)d_in[9];
    const float* b2  = (const float*)d_in[10];
    const float* Wc  = (const float*)d_in[11];
    const float* bc  = (const float*)d_in[12];
    float* out = (float*)d_out;

    char* ws = (char*)d_ws;
    size_t off = 0;
    auto alloc = [&](size_t b) { char* p = ws + off; off += (b + 255) & ~(size_t)255; return p; };
    // bh (256 w) | gcur (256 w)  -- zeroed by gat_zero (1 block)
    int* bh   = (int*)alloc(512 * 4);
    int* gcur = bh + 256;
    // sums -- zeroed by binA's extra blocks
    float* sums = (float*)alloc((size_t)SUMW * 4);

    unsigned char*  h1f8  = (unsigned char*)alloc((size_t)NN * C1);
    unsigned short* out1b = (unsigned short*)alloc((size_t)NN * C1 * 2);
    unsigned char*  h2f8  = (unsigned char*)alloc((size_t)NN * O2);
    unsigned short* w1t   = (unsigned short*)alloc((size_t)C1 * INC * 2);
    unsigned short* w2t   = (unsigned short*)alloc((size_t)O2 * C1 * 2);
    float* aS1    = (float*)alloc((size_t)NN * 2 * 4);
    float* aD1    = (float*)alloc((size_t)NN * 2 * 4);
    float* aS2    = (float*)alloc((size_t)NN * 4);
    float* aD2    = (float*)alloc((size_t)NN * 4);
    int*   rowptr = (int*)alloc((size_t)(NN + 1) * 4);
    int*   bb     = (int*)alloc(256 * 4);
    unsigned* csru = (unsigned*)alloc((size_t)NE * 4);
    unsigned* ebuf = (unsigned*)alloc((size_t)NE * 4);
    float2* eb1   = (float2*)alloc((size_t)NE * 16);   // [2][NE] float2
    float2* eb2   = (float2*)alloc((size_t)NE * 8);
    int*   bnds   = (int*)alloc(65 * 4);
    if (off > ws_size) return;

    // --- zero bh|gcur (tiny) ---
    gat_zero<<<1, 128, 0, stream>>>((float4*)bh);

    // --- fused prep: 196-bucket histogram | W transpose + bounds ---
    gat_prep<<<PB_HB + PB_W, 256, 0, stream>>>(ei, W1, W2, bat, bh, w1t, w2t, bnds);

    // --- bucket bases + counting sort (binA also zeroes sums) ---
    gat_scanb<<<1, 256, 0, stream>>>(bh, bb);
    gat_binA<<<NBA + SUMQ / 256, 256, 0, stream>>>(ei, bb, gcur, ebuf, (float4*)sums);
    gat_binB_gemm1<<<NBKT + (NN + 63) / 64, 256, 0, stream>>>(ebuf, bb, rowptr, csru,
                                                              x, w1t, as1, ad1,
                                                              h1f8, aS1, aD1);

    // --- per-edge records, layer 1 (streaming, split per head) ---
    gat_e1<<<NE / 256, 256, 0, stream>>>(csru, (const float2*)aS1, (const float2*)aD1, eb1);

    // --- layer 1 aggregation (1 dst/wave, 16 edges in flight, pk_fma) ---
    gat_agg1<<<NN / 4, 256, 0, stream>>>(rowptr, eb1, h1f8, out1b);

    // --- layer 2 gemm + att2 ---
    gat_gemm2<<<(NN + 63) / 64, 256, 0, stream>>>(out1b, b1, w2t, as2, ad2,
                                                  h2f8, aS2, aD2);

    // --- per-edge records, layer 2 (streaming) ---
    gat_e2<<<NE / 256, 256, 0, stream>>>(csru, aS2, aD2, eb2);

    // --- layer 2 aggregation + fused pooling ---
    gat_agg2<<<NN / 4, 256, 0, stream>>>(rowptr, eb2, h2f8, bat, b2, sums);

    // --- classify ---
    gat_cls<<<NG, 64, 0, stream>>>(sums, bnds, Wc, bc, out);
}

// Round 7
// 165.715 us; speedup vs baseline: 1.0068x; 1.0068x over previous
//
#include <hip/hip_runtime.h>
#include <cmath>

#define NN 50000
#define NE 800000
#define INC 128
#define C1 256
#define O2 64
#define NG 64
#define NSLOT 64      // pooling atomic slots
#define NBKT 196      // CSR sort buckets: 256 dsts each
#define CHUNK 2048    // edges per binA block
#define NBA ((NE + CHUNK - 1) / CHUNK)   // 391 binA sort blocks
#define SUMW (NSLOT * NG * O2)           // 262144 words
#define SUMQ (SUMW / 4)                  // 65536 quads -> 256 blocks
#define PB_HB 256     // histogram blocks in prep
#define EPB (NE / PB_HB)  // 3125 edges per hist block (exact)
#define PB_W 193      // W-transpose + bounds blocks

typedef short bf16x8 __attribute__((ext_vector_type(8)));
typedef float f32x4 __attribute__((ext_vector_type(4)));
typedef float f32x2 __attribute__((ext_vector_type(2)));

__device__ __forceinline__ float lrelu02(float x) { return x >= 0.f ? x : 0.2f * x; }
__device__ __forceinline__ float eluf(float x) { return x > 0.f ? x : expm1f(x); }
__device__ __forceinline__ unsigned short f2bf(float f) {
    unsigned u = __float_as_uint(f);
    u += 0x7fffu + ((u >> 16) & 1u);
    return (unsigned short)(u >> 16);
}
__device__ __forceinline__ float bf2f(unsigned short s) {
    return __uint_as_float(((unsigned)s) << 16);
}

// ---- fp8 e4m3 encode/decode (HW converts on gfx950; SW fallback) ----
__device__ __forceinline__ unsigned char f2fp8(float f) {
#if __has_builtin(__builtin_amdgcn_cvt_pk_fp8_f32)
    return (unsigned char)(__builtin_amdgcn_cvt_pk_fp8_f32(f, f, 0, false) & 0xff);
#else
    unsigned u = __float_as_uint(f);
    unsigned s = u >> 31;
    float a = fabsf(f);
    int e = ((u >> 23) & 255) - 127;
    if (e < -6) {
        int q = (int)rintf(ldexpf(a, 9));
        return (unsigned char)((s << 7) | (unsigned)q);
    }
    unsigned m = u & 0x7fffffu;
    const unsigned keep = 20;
    unsigned mr = m + ((1u << (keep - 1)) - 1 + ((m >> keep) & 1));
    if (mr >> 23) { e += 1; mr = 0; }
    unsigned m3 = (mr >> keep) & 7;
    if (e > 8) { e = 8; m3 = 6; }
    return (unsigned char)((s << 7) | ((unsigned)(e + 7) << 3) | m3);
#endif
}
__device__ __forceinline__ float fp81(unsigned b) {
#if __has_builtin(__builtin_amdgcn_cvt_f32_fp8)
    return __builtin_amdgcn_cvt_f32_fp8((int)b, 0);
#else
    unsigned s = (b >> 7) & 1, e = (b >> 3) & 15, m = b & 7;
    float v = (e == 0) ? ldexpf((float)m, -9) : ldexpf((float)(8 + m), (int)e - 10);
    return s ? -v : v;
#endif
}
__device__ __forceinline__ float4 fp8x4(unsigned uu) {
#if __has_builtin(__builtin_amdgcn_cvt_pk_f32_fp8)
    f32x2 lo = __builtin_amdgcn_cvt_pk_f32_fp8(uu, false);
    f32x2 hi = __builtin_amdgcn_cvt_pk_f32_fp8(uu, true);
    return make_float4(lo[0], lo[1], hi[0], hi[1]);
#else
    return make_float4(fp81(uu & 255), fp81((uu >> 8) & 255),
                       fp81((uu >> 16) & 255), fp81(uu >> 24));
#endif
}

// ---- zero bh|gcur (512 words = 128 quads, one block) ----
__global__ __launch_bounds__(128) void gat_zero(float4* __restrict__ z) {
    z[threadIdx.x] = make_float4(0.f, 0.f, 0.f, 0.f);
}

// ---- fused prep: [0,256) bucket histogram (196 buckets) | [256,449) W transpose + bounds ----
__global__ __launch_bounds__(256) void gat_prep(const int* __restrict__ ei,
                                                const float* __restrict__ W1,
                                                const float* __restrict__ W2,
                                                const int* __restrict__ batch,
                                                int* __restrict__ bh,
                                                unsigned short* __restrict__ w1t,
                                                unsigned short* __restrict__ w2t,
                                                int* __restrict__ bnds) {
    int b = blockIdx.x, t = threadIdx.x;
    if (b < PB_HB) {
        __shared__ int h[256];
        h[t] = 0;
        __syncthreads();
        int j0 = b * EPB;
        for (int k = t; k < EPB; k += 256)
            atomicAdd(&h[ei[NE + j0 + k] >> 8], 1);
        __syncthreads();
        if (t < NBKT && h[t] > 0) atomicAdd(bh + t, h[t]);
    } else {
        int bb_ = b - PB_HB;
        if (bb_ < 128) {                     // w1t[256][128] = W1^T
            int idx = bb_ * 256 + t;
            int n = idx >> 7, k = idx & 127;
            w1t[idx] = f2bf(W1[(size_t)k * C1 + n]);
        } else if (bb_ < 192) {              // w2t[64][256] = W2^T
            int idx = (bb_ - 128) * 256 + t;
            int n = idx >> 8, k = idx & 255;
            w2t[idx] = f2bf(W2[(size_t)k * O2 + n]);
        } else {
            if (t <= NG) {
                int lo = 0, hi = NN;
                while (lo < hi) {
                    int mid = (lo + hi) >> 1;
                    if (batch[mid] < t) lo = mid + 1; else hi = mid;
                }
                bnds[t] = lo;
            }
        }
    }
}

// ---- scan of 196 bucket counts -> bucket bases bb[0..196] ----
__global__ __launch_bounds__(256) void gat_scanb(const int* __restrict__ bh,
                                                 int* __restrict__ bb) {
    __shared__ int lds[256];
    int t = threadIdx.x;
    int v = (t < NBKT) ? bh[t] : 0;
    lds[t] = v;
    __syncthreads();
#pragma unroll
    for (int o = 1; o < 256; o <<= 1) {
        int add = (t >= o) ? lds[t - o] : 0;
        __syncthreads();
        lds[t] += add;
        __syncthreads();
    }
    if (t <= NBKT) bb[t] = lds[t] - v;   // exclusive; bb[196] = NE
}

// ---- CSR build phase A: counting sort by bucket; extra blocks zero `sums` ----
__global__ __launch_bounds__(256) void gat_binA(const int* __restrict__ ei,
                                                const int* __restrict__ bb,
                                                int* __restrict__ gcur,
                                                unsigned* __restrict__ ebuf,
                                                float4* __restrict__ sumsq) {
    __shared__ int hist[256], lofs[256], gofs[256], fill[256];
    __shared__ unsigned stage[CHUNK];
    const int t = threadIdx.x;
    if (blockIdx.x >= NBA) {                 // sums-zero blocks (overlapped with sort)
        int i = (blockIdx.x - NBA) * 256 + t;
        sumsq[i] = make_float4(0.f, 0.f, 0.f, 0.f);
        return;
    }
    const int j0 = blockIdx.x * CHUNK;
    const int n = min(CHUNK, NE - j0);
    hist[t] = 0;
    __syncthreads();
    for (int k = t; k < n; k += 256)
        atomicAdd(&hist[ei[NE + j0 + k] >> 8], 1);
    __syncthreads();
    int v = hist[t];
    lofs[t] = v;
    __syncthreads();
#pragma unroll
    for (int o = 1; o < 256; o <<= 1) {
        int add = (t >= o) ? lofs[t - o] : 0;
        __syncthreads();
        lofs[t] += add;
        __syncthreads();
    }
    int excl = lofs[t] - v;
    __syncthreads();
    lofs[t] = excl;
    if (t < NBKT && v > 0)
        gofs[t] = bb[t] + atomicAdd(gcur + t, v);
    fill[t] = 0;
    __syncthreads();
    for (int k = t; k < n; k += 256) {
        int j = j0 + k;
        int d = ei[NE + j];
        int s = ei[j];
        int b = d >> 8;
        int r = atomicAdd(&fill[b], 1);
        stage[lofs[b] + r] = (unsigned)s | ((unsigned)(d & 255) << 16) | ((unsigned)b << 24);
    }
    __syncthreads();
    for (int idx = t; idx < n; idx += 256) {
        unsigned u = stage[idx];
        int b = u >> 24;
        ebuf[gofs[b] + (idx - lofs[b])] = u;
    }
}

// ---- merged launch: blocks [0,NBKT) = binB (per-dst rowptr + placement of the
//      FULL packed word (s|dl|bkt) into csru); blocks [NBKT, ...) = gemm1 ----
__global__ __launch_bounds__(256) void gat_binB_gemm1(
        const unsigned* __restrict__ ebuf, const int* __restrict__ bb,
        int* __restrict__ rowptr, unsigned* __restrict__ csru,
        const float* __restrict__ x, const unsigned short* __restrict__ w1t,
        const float* __restrict__ as1, const float* __restrict__ ad1,
        unsigned char* __restrict__ h1f8, float* __restrict__ aS,
        float* __restrict__ aD) {
    __shared__ unsigned short As[64][136];
    __shared__ unsigned short Bh[64][136];
    __shared__ int cntB[256];
    __shared__ int scB[256];
    const int tid = threadIdx.x;
    if (blockIdx.x < NBKT) {
        const int b = blockIdx.x, t = tid;
        const int base = bb[b], end = bb[b + 1];
        cntB[t] = 0;
        __syncthreads();
        for (int idx = base + t; idx < end; idx += 256)
            atomicAdd(&cntB[(ebuf[idx] >> 16) & 255], 1);
        __syncthreads();
        int v = cntB[t];
        scB[t] = v;
        __syncthreads();
#pragma unroll
        for (int o = 1; o < 256; o <<= 1) {
            int add = (t >= o) ? scB[t - o] : 0;
            __syncthreads();
            scB[t] += add;
            __syncthreads();
        }
        int rp = base + scB[t] - v;      // global CSR start for dst (b<<8)+t
        __syncthreads();
        scB[t] = rp;
        int d = (b << 8) + t;
        if (d < NN) rowptr[d] = rp;
        if (b == 0 && t == 0) rowptr[NN] = NE;
        cntB[t] = 0;
        __syncthreads();
        for (int idx = base + t; idx < end; idx += 256) {
            unsigned u = ebuf[idx];
            int dl = (u >> 16) & 255;
            int r = atomicAdd(&cntB[dl], 1);
            csru[scB[dl] + r] = u;       // keep full (s | dl<<16 | bkt<<24)
        }
        return;
    }
    const int m0 = (blockIdx.x - NBKT) * 64;
    const int seg = tid & 15, r = tid >> 4;
#pragma unroll
    for (int i = 0; i < 4; ++i) {
        int rr = r + i * 16, gr = m0 + rr;
        ushort4 o0 = {0, 0, 0, 0}, o1 = {0, 0, 0, 0};
        if (gr < NN) {
            const float* p = x + (size_t)gr * INC + seg * 8;
            float4 v0 = *(const float4*)p;
            float4 v1 = *(const float4*)(p + 4);
            o0.x = f2bf(v0.x); o0.y = f2bf(v0.y); o0.z = f2bf(v0.z); o0.w = f2bf(v0.w);
            o1.x = f2bf(v1.x); o1.y = f2bf(v1.y); o1.z = f2bf(v1.z); o1.w = f2bf(v1.w);
        }
        *(ushort4*)&As[rr][seg * 8] = o0;
        *(ushort4*)&As[rr][seg * 8 + 4] = o1;
    }
    __syncthreads();
    const int lane = tid & 63, w = tid >> 6;
    const int lr = lane & 15, lk = (lane >> 4) * 8;
    bf16x8 a[4];
#pragma unroll
    for (int q = 0; q < 4; ++q)
        a[q] = *(const bf16x8*)&As[w * 16 + lr][q * 32 + lk];
    const int rbase = m0 + w * 16 + (lane >> 4) * 4;
    float psH[2][4] = {}, pdH[2][4] = {};
    for (int it = 0; it < 4; ++it) {
        const int n0 = it * 64;
        if (it > 0) __syncthreads();
        {
#pragma unroll
            for (int i = 0; i < 4; ++i) {
                int nr = r + i * 16;
                *(int4*)&Bh[nr][seg * 8] = *(const int4*)(w1t + (size_t)(n0 + nr) * INC + seg * 8);
            }
        }
        __syncthreads();
        f32x4 acc[4] = {};
#pragma unroll
        for (int j = 0; j < 4; ++j) {
#pragma unroll
            for (int q = 0; q < 4; ++q) {
                bf16x8 bh = *(const bf16x8*)&Bh[j * 16 + lr][q * 32 + lk];
                acc[j] = __builtin_amdgcn_mfma_f32_16x16x32_bf16(a[q], bh, acc[j], 0, 0, 0);
            }
        }
#pragma unroll
        for (int j = 0; j < 4; ++j) {
            int col = n0 + j * 16 + lr;
#pragma unroll
            for (int r4 = 0; r4 < 4; ++r4) {
                int gr = rbase + r4;
                if (gr < NN) h1f8[(size_t)gr * C1 + col] = f2fp8(acc[j][r4]);
            }
        }
        const int head = n0 >> 7;
        float attS[4], attD[4];
#pragma unroll
        for (int j = 0; j < 4; ++j) {
            attS[j] = as1[n0 + j * 16 + lr];
            attD[j] = ad1[n0 + j * 16 + lr];
        }
#pragma unroll
        for (int r4 = 0; r4 < 4; ++r4) {
#pragma unroll
            for (int j = 0; j < 4; ++j) {
                psH[head][r4] = fmaf(acc[j][r4], attS[j], psH[head][r4]);
                pdH[head][r4] = fmaf(acc[j][r4], attD[j], pdH[head][r4]);
            }
        }
    }
#pragma unroll
    for (int r4 = 0; r4 < 4; ++r4) {
        float p0 = psH[0][r4], p1 = psH[1][r4];
        float d0 = pdH[0][r4], d1 = pdH[1][r4];
#pragma unroll
        for (int o = 1; o < 16; o <<= 1) {
            p0 += __shfl_xor(p0, o, 64);
            p1 += __shfl_xor(p1, o, 64);
            d0 += __shfl_xor(d0, o, 64);
            d1 += __shfl_xor(d1, o, 64);
        }
        if (lr == 0) {
            int gr = rbase + r4;
            if (gr < NN) {
                *(float2*)(aS + (size_t)gr * 2) = make_float2(p0, p1);
                *(float2*)(aD + (size_t)gr * 2) = make_float2(d0, d1);
            }
        }
    }
}

// ---- streaming per-edge record, layer 1: {e_head0, e_head1, s*256 (byte offset)} ----
__global__ __launch_bounds__(256) void gat_e1(const unsigned* __restrict__ csru,
                                              const float2* __restrict__ aS,
                                              const float2* __restrict__ aD,
                                              float4* __restrict__ eb) {
    int j = blockIdx.x * 256 + threadIdx.x;
    unsigned u = csru[j];
    unsigned s = u & 0xffffu;
    int d = (int)((u >> 24) << 8) | (int)((u >> 16) & 255u);
    float2 as_ = aS[s];
    float2 ad_ = aD[d];
    eb[j] = make_float4(__expf(lrelu02(as_.x + ad_.x)),
                        __expf(lrelu02(as_.y + ad_.y)),
                        __uint_as_float(s << 8), 0.f);
}

// ---- streaming per-edge record, layer 2: {e, s*64 (byte offset)} ----
__global__ __launch_bounds__(256) void gat_e2(const unsigned* __restrict__ csru,
                                              const float* __restrict__ aS,
                                              const float* __restrict__ aD,
                                              float2* __restrict__ eb) {
    int j = blockIdx.x * 256 + threadIdx.x;
    unsigned u = csru[j];
    unsigned s = u & 0xffffu;
    int d = (int)((u >> 24) << 8) | (int)((u >> 16) & 255u);
    eb[j] = make_float2(__expf(lrelu02(aS[s] + aD[d])),
                        __uint_as_float(s << 6));
}

// --- GEMM2 (MFMA) + fused att2 (full row per block, direct store); h2 out fp8 ---
__global__ __launch_bounds__(256) void gat_gemm2(const unsigned short* __restrict__ out1b,
                                                 const float* __restrict__ b1,
                                                 const unsigned short* __restrict__ w2t,
                                                 const float* __restrict__ as2,
                                                 const float* __restrict__ ad2,
                                                 unsigned char* __restrict__ h2f8,
                                                 float* __restrict__ aS,
                                                 float* __restrict__ aD) {
    __shared__ unsigned short As[64][136];
    __shared__ unsigned short Bh[64][136];
    const int m0 = blockIdx.x * 64;
    const int tid = threadIdx.x;
    const int lane = tid & 63, w = tid >> 6;
    const int lr = lane & 15, lk = (lane >> 4) * 8;
    f32x4 acc[4] = {};
    for (int kc = 0; kc < 2; ++kc) {
        __syncthreads();
        {
            int seg = tid & 15, r = tid >> 4;
            float4 bia0 = *(const float4*)(b1 + kc * 128 + seg * 8);
            float4 bia1 = *(const float4*)(b1 + kc * 128 + seg * 8 + 4);
#pragma unroll
            for (int i = 0; i < 4; ++i) {
                int rr = r + i * 16, gr = m0 + rr;
                ushort4 o0 = {0, 0, 0, 0}, o1 = {0, 0, 0, 0};
                if (gr < NN) {
                    const unsigned short* p = out1b + (size_t)gr * C1 + kc * 128 + seg * 8;
                    ushort4 u0 = *(const ushort4*)p;
                    ushort4 u1 = *(const ushort4*)(p + 4);
                    o0.x = f2bf(eluf(bf2f(u0.x) + bia0.x));
                    o0.y = f2bf(eluf(bf2f(u0.y) + bia0.y));
                    o0.z = f2bf(eluf(bf2f(u0.z) + bia0.z));
                    o0.w = f2bf(eluf(bf2f(u0.w) + bia0.w));
                    o1.x = f2bf(eluf(bf2f(u1.x) + bia1.x));
                    o1.y = f2bf(eluf(bf2f(u1.y) + bia1.y));
                    o1.z = f2bf(eluf(bf2f(u1.z) + bia1.z));
                    o1.w = f2bf(eluf(bf2f(u1.w) + bia1.w));
                }
                *(ushort4*)&As[rr][seg * 8] = o0;
                *(ushort4*)&As[rr][seg * 8 + 4] = o1;
            }
#pragma unroll
            for (int i = 0; i < 4; ++i) {
                int nr = r + i * 16;
                *(int4*)&Bh[nr][seg * 8] = *(const int4*)(w2t + (size_t)nr * C1 + kc * 128 + seg * 8);
            }
        }
        __syncthreads();
        bf16x8 a[4];
#pragma unroll
        for (int q = 0; q < 4; ++q)
            a[q] = *(const bf16x8*)&As[w * 16 + lr][q * 32 + lk];
#pragma unroll
        for (int j = 0; j < 4; ++j) {
#pragma unroll
            for (int q = 0; q < 4; ++q) {
                bf16x8 bh = *(const bf16x8*)&Bh[j * 16 + lr][q * 32 + lk];
                acc[j] = __builtin_amdgcn_mfma_f32_16x16x32_bf16(a[q], bh, acc[j], 0, 0, 0);
            }
        }
    }
    const int rbase = m0 + w * 16 + (lane >> 4) * 4;
#pragma unroll
    for (int j = 0; j < 4; ++j) {
        int col = j * 16 + lr;
#pragma unroll
        for (int r4 = 0; r4 < 4; ++r4) {
            int gr = rbase + r4;
            if (gr < NN) h2f8[(size_t)gr * O2 + col] = f2fp8(acc[j][r4]);
        }
    }
    float attS[4], attD[4];
#pragma unroll
    for (int j = 0; j < 4; ++j) {
        attS[j] = as2[j * 16 + lr];
        attD[j] = ad2[j * 16 + lr];
    }
#pragma unroll
    for (int r4 = 0; r4 < 4; ++r4) {
        float ps = 0.f, pd = 0.f;
#pragma unroll
        for (int j = 0; j < 4; ++j) {
            ps = fmaf(acc[j][r4], attS[j], ps);
            pd = fmaf(acc[j][r4], attD[j], pd);
        }
#pragma unroll
        for (int o = 1; o < 16; o <<= 1) {
            ps += __shfl_xor(ps, o, 64);
            pd += __shfl_xor(pd, o, 64);
        }
        if (lr == 0) {
            int gr = rbase + r4;
            if (gr < NN) { aS[gr] = ps; aD[gr] = pd; }
        }
    }
}

// ------- aggregation layer 1: 2 dsts/wave (32-lane groups, 8 fp8 ch/lane),
//         self-contained edge records (uniform float4 load -> e + gather offset),
//         8-deep batches with a 2-STAGE SOFTWARE PIPELINE: batch n+1's records
//         and gathers are issued while batch n's FMAs run. Zero shuffles,
//         zero exp; sd is lane-uniform (no reduction). -------
__global__ __launch_bounds__(256) void gat_agg1(const int* __restrict__ rowptr,
                                                const float4* __restrict__ eb1,
                                                const unsigned char* __restrict__ h1f8,
                                                unsigned short* __restrict__ out1b) {
    const int wid = threadIdx.x >> 6, lane = threadIdx.x & 63;
    const int grp = lane >> 5, li = lane & 31;
    const int d = (blockIdx.x * 4 + wid) * 2 + grp;   // 6250 blocks * 8 = 50000 exact
    const int st = rowptr[d], en = rowptr[d + 1];
    const int coff = li << 3;              // 8 fp8 channels per lane (byte offset)
    const bool hi = li >= 16;              // head1 lanes (channels >= 128)
    float a0 = 0.f, a1 = 0.f, a2 = 0.f, a3 = 0.f;
    float a4 = 0.f, a5 = 0.f, a6 = 0.f, a7 = 0.f;
    float sd = 0.f;
    const int en1 = en - 1;
    if (st < en) {
        float m[8]; uint2 v[8];
        // stage 0: batch at st
#pragma unroll
        for (int k = 0; k < 8; ++k) {
            int j = st + k, jc = min(j, en1);
            float4 qq = eb1[jc];
            v[k] = *(const uint2*)(h1f8 + (size_t)__float_as_uint(qq.z) + coff);
            m[k] = (j <= en1) ? (hi ? qq.y : qq.x) : 0.f;
        }
        for (int i = st;;) {
            const int ni = i + 8;
            const bool more = ni < en;
            float mN[8]; uint2 vN[8];
            if (more) {                    // issue next batch while current FMAs run
#pragma unroll
                for (int k = 0; k < 8; ++k) {
                    int j = ni + k, jc = min(j, en1);
                    float4 qq = eb1[jc];
                    vN[k] = *(const uint2*)(h1f8 + (size_t)__float_as_uint(qq.z) + coff);
                    mN[k] = (j <= en1) ? (hi ? qq.y : qq.x) : 0.f;
                }
            }
#pragma unroll
            for (int k = 0; k < 8; ++k) {
                float mk = m[k];
                sd += mk;
                float4 w0 = fp8x4(v[k].x), w1 = fp8x4(v[k].y);
                a0 = fmaf(w0.x, mk, a0); a1 = fmaf(w0.y, mk, a1);
                a2 = fmaf(w0.z, mk, a2); a3 = fmaf(w0.w, mk, a3);
                a4 = fmaf(w1.x, mk, a4); a5 = fmaf(w1.y, mk, a5);
                a6 = fmaf(w1.z, mk, a6); a7 = fmaf(w1.w, mk, a7);
            }
            if (!more) break;
#pragma unroll
            for (int k = 0; k < 8; ++k) { m[k] = mN[k]; v[k] = vN[k]; }
            i = ni;
        }
    }
    float inv = 1.f / (sd + 1e-16f);
    ushort4 o0, o1;
    o0.x = f2bf(a0 * inv); o0.y = f2bf(a1 * inv);
    o0.z = f2bf(a2 * inv); o0.w = f2bf(a3 * inv);
    o1.x = f2bf(a4 * inv); o1.y = f2bf(a5 * inv);
    o1.z = f2bf(a6 * inv); o1.w = f2bf(a7 * inv);
    *(ushort4*)(out1b + (size_t)d * C1 + coff) = o0;
    *(ushort4*)(out1b + (size_t)d * C1 + coff + 4) = o1;
}

// ------- aggregation layer 2: 1 dst/WAVE, 4 edge-quadrants x 16 channel-lanes,
//         self-contained records, 16 edges in flight (4/quadrant); 2 shfl_xor
//         reductions at the end; pooling merges 4 dsts -> 1 atomic/channel. -------
__global__ __launch_bounds__(256) void gat_agg2(const int* __restrict__ rowptr,
                                                const float2* __restrict__ eb2,
                                                const unsigned char* __restrict__ h2f8,
                                                const int* __restrict__ batch,
                                                const float* __restrict__ b2,
                                                float* __restrict__ sums) {
    __shared__ float pool[4][64];
    const int wid = threadIdx.x >> 6, lane = threadIdx.x & 63;
    const int eq = lane >> 4;              // edge quadrant 0..3
    const int li = lane & 15;              // channel lane
    const int c = li << 2;                 // 4 channels per lane (byte offset)
    const int d = blockIdx.x * 4 + wid;    // 12500 blocks * 4 = 50000 exact
    const int st = rowptr[d], en = rowptr[d + 1];
    float a0 = 0.f, a1 = 0.f, a2 = 0.f, a3 = 0.f;
    float sd = 0.f;
    const int en1 = en - 1;
    for (int i = st; i < en; i += 16) {
        int j0 = i + eq, j1 = j0 + 4, j2 = j0 + 8, j3 = j0 + 12;
        int c0 = min(j0, en1), c1 = min(j1, en1), c2 = min(j2, en1), c3 = min(j3, en1);
        float2 q0 = eb2[c0], q1 = eb2[c1], q2 = eb2[c2], q3 = eb2[c3];
        unsigned v0 = *(const unsigned*)(h2f8 + (size_t)__float_as_uint(q0.y) + c);
        unsigned v1 = *(const unsigned*)(h2f8 + (size_t)__float_as_uint(q1.y) + c);
        unsigned v2 = *(const unsigned*)(h2f8 + (size_t)__float_as_uint(q2.y) + c);
        unsigned v3 = *(const unsigned*)(h2f8 + (size_t)__float_as_uint(q3.y) + c);
        float m0 = (j0 <= en1) ? q0.x : 0.f;
        float m1 = (j1 <= en1) ? q1.x : 0.f;
        float m2 = (j2 <= en1) ? q2.x : 0.f;
        float m3 = (j3 <= en1) ? q3.x : 0.f;
        sd += (m0 + m1) + (m2 + m3);
        float4 w;
        w = fp8x4(v0);
        a0 = fmaf(w.x, m0, a0); a1 = fmaf(w.y, m0, a1);
        a2 = fmaf(w.z, m0, a2); a3 = fmaf(w.w, m0, a3);
        w = fp8x4(v1);
        a0 = fmaf(w.x, m1, a0); a1 = fmaf(w.y, m1, a1);
        a2 = fmaf(w.z, m1, a2); a3 = fmaf(w.w, m1, a3);
        w = fp8x4(v2);
        a0 = fmaf(w.x, m2, a0); a1 = fmaf(w.y, m2, a1);
        a2 = fmaf(w.z, m2, a2); a3 = fmaf(w.w, m2, a3);
        w = fp8x4(v3);
        a0 = fmaf(w.x, m3, a0); a1 = fmaf(w.y, m3, a1);
        a2 = fmaf(w.z, m3, a2); a3 = fmaf(w.w, m3, a3);
    }
    // reduce over the 4 edge-quadrants (lanes ^16, ^32 share channels)
    a0 += __shfl_xor(a0, 16, 64); a0 += __shfl_xor(a0, 32, 64);
    a1 += __shfl_xor(a1, 16, 64); a1 += __shfl_xor(a1, 32, 64);
    a2 += __shfl_xor(a2, 16, 64); a2 += __shfl_xor(a2, 32, 64);
    a3 += __shfl_xor(a3, 16, 64); a3 += __shfl_xor(a3, 32, 64);
    sd += __shfl_xor(sd, 16, 64); sd += __shfl_xor(sd, 32, 64);
    float inv = 1.f / (sd + 1e-16f);
    if (eq == 0)
        *(float4*)&pool[wid][c] = make_float4(a0 * inv, a1 * inv, a2 * inv, a3 * inv);
    __syncthreads();
    const int slot = blockIdx.x & (NSLOT - 1);
    const int d0 = blockIdx.x * 4;
    int g0 = batch[d0], g3 = batch[d0 + 3];
    if (g0 == g3) {                        // common case (sorted batch): 1 atomic/channel
        if (threadIdx.x < 64) {
            int ch = threadIdx.x;
            float bb_ = b2[ch];
            float v = 0.f;
#pragma unroll
            for (int r = 0; r < 4; ++r) {
                float t = pool[r][ch] + bb_;
                v += (t > 0.f) ? t : expm1f(t);
            }
            unsafeAtomicAdd(sums + ((size_t)slot * NG + g0) * O2 + ch, v);
        }
    } else {                               // graph boundary inside block (rare)
        int r = threadIdx.x >> 6, ch = threadIdx.x & 63;
        float t = pool[r][ch] + b2[ch];
        t = (t > 0.f) ? t : expm1f(t);
        unsafeAtomicAdd(sums + ((size_t)slot * NG + batch[d0 + r]) * O2 + ch, t);
    }
}

// ------- classifier: reduce slots, mean, @Wc + bc -------
__global__ __launch_bounds__(64) void gat_cls(const float* __restrict__ sums,
                                              const int* __restrict__ bnds,
                                              const float* __restrict__ Wc,
                                              const float* __restrict__ bc,
                                              float* __restrict__ out) {
    int g = blockIdx.x, c = threadIdx.x;
    float s = 0.f;
#pragma unroll
    for (int sl = 0; sl < NSLOT; ++sl)
        s += sums[((size_t)sl * NG + g) * O2 + c];
    float cnt = (float)(bnds[g + 1] - bnds[g]);
    float p = s / fmaxf(cnt, 1.f);
    float p0 = p * Wc[c * 2 + 0];
    float p1 = p * Wc[c * 2 + 1];
#pragma unroll
    for (int off = 1; off < 64; off <<= 1) {
        p0 += __shfl_xor(p0, off, 64);
        p1 += __shfl_xor(p1, off, 64);
    }
    if (c == 0) {
        out[g * 2 + 0] = p0 + bc[0];
        out[g * 2 + 1] = p1 + bc[1];
    }
}

extern "C" void kernel_launch(void* const* d_in, const int* in_sizes, int n_in,
                              void* d_out, int out_size, void* d_ws, size_t ws_size,
                              hipStream_t stream) {
    const float* x   = (const float*)d_in[0];
    const int*   ei  = (const int*)d_in[1];
    const int*   bat = (const int*)d_in[2];
    const float* W1  = (const float*)d_in[3];
    const float* as1 = (const float*)d_in[4];
    const float* ad1 = (const float*)d_in[5];
    const float* b1  = (const float*)d_in[6];
    const float* W2  = (const float*)d_in[7];
    const float* as2 = (const float*)d_in[8];
    const float* ad2 = (const float*)d_in[9];
    const float* b2  = (const float*)d_in[10];
    const float* Wc  = (const float*)d_in[11];
    const float* bc  = (const float*)d_in[12];
    float* out = (float*)d_out;

    char* ws = (char*)d_ws;
    size_t off = 0;
    auto alloc = [&](size_t b) { char* p = ws + off; off += (b + 255) & ~(size_t)255; return p; };
    // bh (256 w) | gcur (256 w)  -- zeroed by gat_zero (1 block)
    int* bh   = (int*)alloc(512 * 4);
    int* gcur = bh + 256;
    // sums -- zeroed by binA's extra blocks
    float* sums = (float*)alloc((size_t)SUMW * 4);

    unsigned char*  h1f8  = (unsigned char*)alloc((size_t)NN * C1);
    unsigned short* out1b = (unsigned short*)alloc((size_t)NN * C1 * 2);
    unsigned char*  h2f8  = (unsigned char*)alloc((size_t)NN * O2);
    unsigned short* w1t   = (unsigned short*)alloc((size_t)C1 * INC * 2);
    unsigned short* w2t   = (unsigned short*)alloc((size_t)O2 * C1 * 2);
    float* aS1    = (float*)alloc((size_t)NN * 2 * 4);
    float* aD1    = (float*)alloc((size_t)NN * 2 * 4);
    float* aS2    = (float*)alloc((size_t)NN * 4);
    float* aD2    = (float*)alloc((size_t)NN * 4);
    int*   rowptr = (int*)alloc((size_t)(NN + 1) * 4);
    int*   bb     = (int*)alloc(256 * 4);
    unsigned* csru = (unsigned*)alloc((size_t)NE * 4);
    unsigned* ebuf = (unsigned*)alloc((size_t)NE * 4);
    float4* eb1   = (float4*)alloc((size_t)NE * 16);
    float2* eb2   = (float2*)alloc((size_t)NE * 8);
    int*   bnds   = (int*)alloc(65 * 4);
    if (off > ws_size) return;

    // --- zero bh|gcur (tiny) ---
    gat_zero<<<1, 128, 0, stream>>>((float4*)bh);

    // --- fused prep: 196-bucket histogram | W transpose + bounds ---
    gat_prep<<<PB_HB + PB_W, 256, 0, stream>>>(ei, W1, W2, bat, bh, w1t, w2t, bnds);

    // --- bucket bases + counting sort (binA also zeroes sums) ---
    gat_scanb<<<1, 256, 0, stream>>>(bh, bb);
    gat_binA<<<NBA + SUMQ / 256, 256, 0, stream>>>(ei, bb, gcur, ebuf, (float4*)sums);
    gat_binB_gemm1<<<NBKT + (NN + 63) / 64, 256, 0, stream>>>(ebuf, bb, rowptr, csru,
                                                              x, w1t, as1, ad1,
                                                              h1f8, aS1, aD1);

    // --- per-edge records, layer 1 (streaming) ---
    gat_e1<<<NE / 256, 256, 0, stream>>>(csru, (const float2*)aS1, (const float2*)aD1, eb1);

    // --- layer 1 aggregation (2 dsts/wave, 8-deep, pipelined record-driven gathers) ---
    gat_agg1<<<NN / 8, 256, 0, stream>>>(rowptr, eb1, h1f8, out1b);

    // --- layer 2 gemm + att2 ---
    gat_gemm2<<<(NN + 63) / 64, 256, 0, stream>>>(out1b, b1, w2t, as2, ad2,
                                                  h2f8, aS2, aD2);

    // --- per-edge records, layer 2 (streaming) ---
    gat_e2<<<NE / 256, 256, 0, stream>>>(csru, aS2, aD2, eb2);

    // --- layer 2 aggregation + fused pooling ---
    gat_agg2<<<NN / 4, 256, 0, stream>>>(rowptr, eb2, h2f8, bat, b2, sums);

    // --- classify ---
    gat_cls<<<NG, 64, 0, stream>>>(sums, bnds, Wc, bc, out);
}

// Round 8
// 153.668 us; speedup vs baseline: 1.0857x; 1.0784x over previous
//
#include <hip/hip_runtime.h>
#include <cmath>

#define NN 50000
#define NE 800000
#define INC 128
#define C1 256
#define O2 64
#define NG 64
#define NSLOT 64      // pooling atomic slots
#define NBKT 196      // CSR sort buckets: 256 dsts each
#define CHUNK 2048    // edges per binA block
#define NBA ((NE + CHUNK - 1) / CHUNK)   // 391 binA sort blocks
#define SUMW (NSLOT * NG * O2)           // 262144 words
#define SUMQ (SUMW / 4)                  // 65536 quads -> 256 blocks
#define PB_HB 256     // histogram blocks in prep
#define EPB (NE / PB_HB)  // 3125 edges per hist block (exact)
#define PB_W 193      // W-transpose + bounds blocks

typedef short bf16x8 __attribute__((ext_vector_type(8)));
typedef float f32x4 __attribute__((ext_vector_type(4)));
typedef float f32x2 __attribute__((ext_vector_type(2)));

__device__ __forceinline__ float lrelu02(float x) { return x >= 0.f ? x : 0.2f * x; }
__device__ __forceinline__ float eluf(float x) { return x > 0.f ? x : expm1f(x); }
__device__ __forceinline__ unsigned short f2bf(float f) {
    unsigned u = __float_as_uint(f);
    u += 0x7fffu + ((u >> 16) & 1u);
    return (unsigned short)(u >> 16);
}
__device__ __forceinline__ float bf2f(unsigned short s) {
    return __uint_as_float(((unsigned)s) << 16);
}

// ---- fp8 e4m3 encode/decode (HW converts on gfx950; SW fallback) ----
__device__ __forceinline__ unsigned char f2fp8(float f) {
#if __has_builtin(__builtin_amdgcn_cvt_pk_fp8_f32)
    return (unsigned char)(__builtin_amdgcn_cvt_pk_fp8_f32(f, f, 0, false) & 0xff);
#else
    unsigned u = __float_as_uint(f);
    unsigned s = u >> 31;
    float a = fabsf(f);
    int e = ((u >> 23) & 255) - 127;
    if (e < -6) {
        int q = (int)rintf(ldexpf(a, 9));
        return (unsigned char)((s << 7) | (unsigned)q);
    }
    unsigned m = u & 0x7fffffu;
    const unsigned keep = 20;
    unsigned mr = m + ((1u << (keep - 1)) - 1 + ((m >> keep) & 1));
    if (mr >> 23) { e += 1; mr = 0; }
    unsigned m3 = (mr >> keep) & 7;
    if (e > 8) { e = 8; m3 = 6; }
    return (unsigned char)((s << 7) | ((unsigned)(e + 7) << 3) | m3);
#endif
}
__device__ __forceinline__ float fp81(unsigned b) {
#if __has_builtin(__builtin_amdgcn_cvt_f32_fp8)
    return __builtin_amdgcn_cvt_f32_fp8((int)b, 0);
#else
    unsigned s = (b >> 7) & 1, e = (b >> 3) & 15, m = b & 7;
    float v = (e == 0) ? ldexpf((float)m, -9) : ldexpf((float)(8 + m), (int)e - 10);
    return s ? -v : v;
#endif
}
__device__ __forceinline__ float4 fp8x4(unsigned uu) {
#if __has_builtin(__builtin_amdgcn_cvt_pk_f32_fp8)
    f32x2 lo = __builtin_amdgcn_cvt_pk_f32_fp8(uu, false);
    f32x2 hi = __builtin_amdgcn_cvt_pk_f32_fp8(uu, true);
    return make_float4(lo[0], lo[1], hi[0], hi[1]);
#else
    return make_float4(fp81(uu & 255), fp81((uu >> 8) & 255),
                       fp81((uu >> 16) & 255), fp81(uu >> 24));
#endif
}

// ---- zero bh|gcur (512 words = 128 quads, one block) ----
__global__ __launch_bounds__(128) void gat_zero(float4* __restrict__ z) {
    z[threadIdx.x] = make_float4(0.f, 0.f, 0.f, 0.f);
}

// ---- fused prep: [0,256) bucket histogram (196 buckets) | [256,449) W transpose + bounds ----
__global__ __launch_bounds__(256) void gat_prep(const int* __restrict__ ei,
                                                const float* __restrict__ W1,
                                                const float* __restrict__ W2,
                                                const int* __restrict__ batch,
                                                int* __restrict__ bh,
                                                unsigned short* __restrict__ w1t,
                                                unsigned short* __restrict__ w2t,
                                                int* __restrict__ bnds) {
    int b = blockIdx.x, t = threadIdx.x;
    if (b < PB_HB) {
        __shared__ int h[256];
        h[t] = 0;
        __syncthreads();
        int j0 = b * EPB;
        for (int k = t; k < EPB; k += 256)
            atomicAdd(&h[ei[NE + j0 + k] >> 8], 1);
        __syncthreads();
        if (t < NBKT && h[t] > 0) atomicAdd(bh + t, h[t]);
    } else {
        int bb_ = b - PB_HB;
        if (bb_ < 128) {                     // w1t[256][128] = W1^T
            int idx = bb_ * 256 + t;
            int n = idx >> 7, k = idx & 127;
            w1t[idx] = f2bf(W1[(size_t)k * C1 + n]);
        } else if (bb_ < 192) {              // w2t[64][256] = W2^T
            int idx = (bb_ - 128) * 256 + t;
            int n = idx >> 8, k = idx & 255;
            w2t[idx] = f2bf(W2[(size_t)k * O2 + n]);
        } else {
            if (t <= NG) {
                int lo = 0, hi = NN;
                while (lo < hi) {
                    int mid = (lo + hi) >> 1;
                    if (batch[mid] < t) lo = mid + 1; else hi = mid;
                }
                bnds[t] = lo;
            }
        }
    }
}

// ---- scan of 196 bucket counts -> bucket bases bb[0..196] ----
__global__ __launch_bounds__(256) void gat_scanb(const int* __restrict__ bh,
                                                 int* __restrict__ bb) {
    __shared__ int lds[256];
    int t = threadIdx.x;
    int v = (t < NBKT) ? bh[t] : 0;
    lds[t] = v;
    __syncthreads();
#pragma unroll
    for (int o = 1; o < 256; o <<= 1) {
        int add = (t >= o) ? lds[t - o] : 0;
        __syncthreads();
        lds[t] += add;
        __syncthreads();
    }
    if (t <= NBKT) bb[t] = lds[t] - v;   // exclusive; bb[196] = NE
}

// ---- CSR build phase A: counting sort by bucket; extra blocks zero `sums` ----
__global__ __launch_bounds__(256) void gat_binA(const int* __restrict__ ei,
                                                const int* __restrict__ bb,
                                                int* __restrict__ gcur,
                                                unsigned* __restrict__ ebuf,
                                                float4* __restrict__ sumsq) {
    __shared__ int hist[256], lofs[256], gofs[256], fill[256];
    __shared__ unsigned stage[CHUNK];
    const int t = threadIdx.x;
    if (blockIdx.x >= NBA) {                 // sums-zero blocks (overlapped with sort)
        int i = (blockIdx.x - NBA) * 256 + t;
        sumsq[i] = make_float4(0.f, 0.f, 0.f, 0.f);
        return;
    }
    const int j0 = blockIdx.x * CHUNK;
    const int n = min(CHUNK, NE - j0);
    hist[t] = 0;
    __syncthreads();
    for (int k = t; k < n; k += 256)
        atomicAdd(&hist[ei[NE + j0 + k] >> 8], 1);
    __syncthreads();
    int v = hist[t];
    lofs[t] = v;
    __syncthreads();
#pragma unroll
    for (int o = 1; o < 256; o <<= 1) {
        int add = (t >= o) ? lofs[t - o] : 0;
        __syncthreads();
        lofs[t] += add;
        __syncthreads();
    }
    int excl = lofs[t] - v;
    __syncthreads();
    lofs[t] = excl;
    if (t < NBKT && v > 0)
        gofs[t] = bb[t] + atomicAdd(gcur + t, v);
    fill[t] = 0;
    __syncthreads();
    for (int k = t; k < n; k += 256) {
        int j = j0 + k;
        int d = ei[NE + j];
        int s = ei[j];
        int b = d >> 8;
        int r = atomicAdd(&fill[b], 1);
        stage[lofs[b] + r] = (unsigned)s | ((unsigned)(d & 255) << 16) | ((unsigned)b << 24);
    }
    __syncthreads();
    for (int idx = t; idx < n; idx += 256) {
        unsigned u = stage[idx];
        int b = u >> 24;
        ebuf[gofs[b] + (idx - lofs[b])] = u;
    }
}

// ---- merged launch: blocks [0,NBKT) = binB (per-dst rowptr + placement of the
//      FULL packed word (s|dl|bkt) into csru); blocks [NBKT, ...) = gemm1 ----
__global__ __launch_bounds__(256) void gat_binB_gemm1(
        const unsigned* __restrict__ ebuf, const int* __restrict__ bb,
        int* __restrict__ rowptr, unsigned* __restrict__ csru,
        const float* __restrict__ x, const unsigned short* __restrict__ w1t,
        const float* __restrict__ as1, const float* __restrict__ ad1,
        unsigned char* __restrict__ h1f8, float* __restrict__ aS,
        float* __restrict__ aD) {
    __shared__ unsigned short As[64][136];
    __shared__ unsigned short Bh[64][136];
    __shared__ int cntB[256];
    __shared__ int scB[256];
    const int tid = threadIdx.x;
    if (blockIdx.x < NBKT) {
        const int b = blockIdx.x, t = tid;
        const int base = bb[b], end = bb[b + 1];
        cntB[t] = 0;
        __syncthreads();
        for (int idx = base + t; idx < end; idx += 256)
            atomicAdd(&cntB[(ebuf[idx] >> 16) & 255], 1);
        __syncthreads();
        int v = cntB[t];
        scB[t] = v;
        __syncthreads();
#pragma unroll
        for (int o = 1; o < 256; o <<= 1) {
            int add = (t >= o) ? scB[t - o] : 0;
            __syncthreads();
            scB[t] += add;
            __syncthreads();
        }
        int rp = base + scB[t] - v;      // global CSR start for dst (b<<8)+t
        __syncthreads();
        scB[t] = rp;
        int d = (b << 8) + t;
        if (d < NN) rowptr[d] = rp;
        if (b == 0 && t == 0) rowptr[NN] = NE;
        cntB[t] = 0;
        __syncthreads();
        for (int idx = base + t; idx < end; idx += 256) {
            unsigned u = ebuf[idx];
            int dl = (u >> 16) & 255;
            int r = atomicAdd(&cntB[dl], 1);
            csru[scB[dl] + r] = u;       // keep full (s | dl<<16 | bkt<<24)
        }
        return;
    }
    const int m0 = (blockIdx.x - NBKT) * 64;
    const int seg = tid & 15, r = tid >> 4;
#pragma unroll
    for (int i = 0; i < 4; ++i) {
        int rr = r + i * 16, gr = m0 + rr;
        ushort4 o0 = {0, 0, 0, 0}, o1 = {0, 0, 0, 0};
        if (gr < NN) {
            const float* p = x + (size_t)gr * INC + seg * 8;
            float4 v0 = *(const float4*)p;
            float4 v1 = *(const float4*)(p + 4);
            o0.x = f2bf(v0.x); o0.y = f2bf(v0.y); o0.z = f2bf(v0.z); o0.w = f2bf(v0.w);
            o1.x = f2bf(v1.x); o1.y = f2bf(v1.y); o1.z = f2bf(v1.z); o1.w = f2bf(v1.w);
        }
        *(ushort4*)&As[rr][seg * 8] = o0;
        *(ushort4*)&As[rr][seg * 8 + 4] = o1;
    }
    __syncthreads();
    const int lane = tid & 63, w = tid >> 6;
    const int lr = lane & 15, lk = (lane >> 4) * 8;
    bf16x8 a[4];
#pragma unroll
    for (int q = 0; q < 4; ++q)
        a[q] = *(const bf16x8*)&As[w * 16 + lr][q * 32 + lk];
    const int rbase = m0 + w * 16 + (lane >> 4) * 4;
    float psH[2][4] = {}, pdH[2][4] = {};
    for (int it = 0; it < 4; ++it) {
        const int n0 = it * 64;
        if (it > 0) __syncthreads();
        {
#pragma unroll
            for (int i = 0; i < 4; ++i) {
                int nr = r + i * 16;
                *(int4*)&Bh[nr][seg * 8] = *(const int4*)(w1t + (size_t)(n0 + nr) * INC + seg * 8);
            }
        }
        __syncthreads();
        f32x4 acc[4] = {};
#pragma unroll
        for (int j = 0; j < 4; ++j) {
#pragma unroll
            for (int q = 0; q < 4; ++q) {
                bf16x8 bh = *(const bf16x8*)&Bh[j * 16 + lr][q * 32 + lk];
                acc[j] = __builtin_amdgcn_mfma_f32_16x16x32_bf16(a[q], bh, acc[j], 0, 0, 0);
            }
        }
#pragma unroll
        for (int j = 0; j < 4; ++j) {
            int col = n0 + j * 16 + lr;
#pragma unroll
            for (int r4 = 0; r4 < 4; ++r4) {
                int gr = rbase + r4;
                if (gr < NN) h1f8[(size_t)gr * C1 + col] = f2fp8(acc[j][r4]);
            }
        }
        const int head = n0 >> 7;
        float attS[4], attD[4];
#pragma unroll
        for (int j = 0; j < 4; ++j) {
            attS[j] = as1[n0 + j * 16 + lr];
            attD[j] = ad1[n0 + j * 16 + lr];
        }
#pragma unroll
        for (int r4 = 0; r4 < 4; ++r4) {
#pragma unroll
            for (int j = 0; j < 4; ++j) {
                psH[head][r4] = fmaf(acc[j][r4], attS[j], psH[head][r4]);
                pdH[head][r4] = fmaf(acc[j][r4], attD[j], pdH[head][r4]);
            }
        }
    }
#pragma unroll
    for (int r4 = 0; r4 < 4; ++r4) {
        float p0 = psH[0][r4], p1 = psH[1][r4];
        float d0 = pdH[0][r4], d1 = pdH[1][r4];
#pragma unroll
        for (int o = 1; o < 16; o <<= 1) {
            p0 += __shfl_xor(p0, o, 64);
            p1 += __shfl_xor(p1, o, 64);
            d0 += __shfl_xor(d0, o, 64);
            d1 += __shfl_xor(d1, o, 64);
        }
        if (lr == 0) {
            int gr = rbase + r4;
            if (gr < NN) {
                *(float2*)(aS + (size_t)gr * 2) = make_float2(p0, p1);
                *(float2*)(aD + (size_t)gr * 2) = make_float2(d0, d1);
            }
        }
    }
}

// ---- streaming per-edge record, layer 2: {e, s*64 (byte offset)} ----
__global__ __launch_bounds__(256) void gat_e2(const unsigned* __restrict__ csru,
                                              const float* __restrict__ aS,
                                              const float* __restrict__ aD,
                                              float2* __restrict__ eb) {
    int j = blockIdx.x * 256 + threadIdx.x;
    unsigned u = csru[j];
    unsigned s = u & 0xffffu;
    int d = (int)((u >> 24) << 8) | (int)((u >> 16) & 255u);
    eb[j] = make_float2(__expf(lrelu02(aS[s] + aD[d])),
                        __uint_as_float(s << 6));
}

// --- GEMM2 (MFMA) + fused att2 (full row per block, direct store); h2 out fp8 ---
__global__ __launch_bounds__(256) void gat_gemm2(const unsigned short* __restrict__ out1b,
                                                 const float* __restrict__ b1,
                                                 const unsigned short* __restrict__ w2t,
                                                 const float* __restrict__ as2,
                                                 const float* __restrict__ ad2,
                                                 unsigned char* __restrict__ h2f8,
                                                 float* __restrict__ aS,
                                                 float* __restrict__ aD) {
    __shared__ unsigned short As[64][136];
    __shared__ unsigned short Bh[64][136];
    const int m0 = blockIdx.x * 64;
    const int tid = threadIdx.x;
    const int lane = tid & 63, w = tid >> 6;
    const int lr = lane & 15, lk = (lane >> 4) * 8;
    f32x4 acc[4] = {};
    for (int kc = 0; kc < 2; ++kc) {
        __syncthreads();
        {
            int seg = tid & 15, r = tid >> 4;
            float4 bia0 = *(const float4*)(b1 + kc * 128 + seg * 8);
            float4 bia1 = *(const float4*)(b1 + kc * 128 + seg * 8 + 4);
#pragma unroll
            for (int i = 0; i < 4; ++i) {
                int rr = r + i * 16, gr = m0 + rr;
                ushort4 o0 = {0, 0, 0, 0}, o1 = {0, 0, 0, 0};
                if (gr < NN) {
                    const unsigned short* p = out1b + (size_t)gr * C1 + kc * 128 + seg * 8;
                    ushort4 u0 = *(const ushort4*)p;
                    ushort4 u1 = *(const ushort4*)(p + 4);
                    o0.x = f2bf(eluf(bf2f(u0.x) + bia0.x));
                    o0.y = f2bf(eluf(bf2f(u0.y) + bia0.y));
                    o0.z = f2bf(eluf(bf2f(u0.z) + bia0.z));
                    o0.w = f2bf(eluf(bf2f(u0.w) + bia0.w));
                    o1.x = f2bf(eluf(bf2f(u1.x) + bia1.x));
                    o1.y = f2bf(eluf(bf2f(u1.y) + bia1.y));
                    o1.z = f2bf(eluf(bf2f(u1.z) + bia1.z));
                    o1.w = f2bf(eluf(bf2f(u1.w) + bia1.w));
                }
                *(ushort4*)&As[rr][seg * 8] = o0;
                *(ushort4*)&As[rr][seg * 8 + 4] = o1;
            }
#pragma unroll
            for (int i = 0; i < 4; ++i) {
                int nr = r + i * 16;
                *(int4*)&Bh[nr][seg * 8] = *(const int4*)(w2t + (size_t)nr * C1 + kc * 128 + seg * 8);
            }
        }
        __syncthreads();
        bf16x8 a[4];
#pragma unroll
        for (int q = 0; q < 4; ++q)
            a[q] = *(const bf16x8*)&As[w * 16 + lr][q * 32 + lk];
#pragma unroll
        for (int j = 0; j < 4; ++j) {
#pragma unroll
            for (int q = 0; q < 4; ++q) {
                bf16x8 bh = *(const bf16x8*)&Bh[j * 16 + lr][q * 32 + lk];
                acc[j] = __builtin_amdgcn_mfma_f32_16x16x32_bf16(a[q], bh, acc[j], 0, 0, 0);
            }
        }
    }
    const int rbase = m0 + w * 16 + (lane >> 4) * 4;
#pragma unroll
    for (int j = 0; j < 4; ++j) {
        int col = j * 16 + lr;
#pragma unroll
        for (int r4 = 0; r4 < 4; ++r4) {
            int gr = rbase + r4;
            if (gr < NN) h2f8[(size_t)gr * O2 + col] = f2fp8(acc[j][r4]);
        }
    }
    float attS[4], attD[4];
#pragma unroll
    for (int j = 0; j < 4; ++j) {
        attS[j] = as2[j * 16 + lr];
        attD[j] = ad2[j * 16 + lr];
    }
#pragma unroll
    for (int r4 = 0; r4 < 4; ++r4) {
        float ps = 0.f, pd = 0.f;
#pragma unroll
        for (int j = 0; j < 4; ++j) {
            ps = fmaf(acc[j][r4], attS[j], ps);
            pd = fmaf(acc[j][r4], attD[j], pd);
        }
#pragma unroll
        for (int o = 1; o < 16; o <<= 1) {
            ps += __shfl_xor(ps, o, 64);
            pd += __shfl_xor(pd, o, 64);
        }
        if (lr == 0) {
            int gr = rbase + r4;
            if (gr < NN) { aS[gr] = ps; aD[gr] = pd; }
        }
    }
}

// ------- aggregation layer 1 (r0-proven structure): 2 dsts/wave (32-lane groups,
//         8 fp8 ch/lane), single pass, deferred norm, 8-way unrolled uint2 gather
//         (256B/row); e computed in-loop and broadcast via shuffles. -------
__global__ __launch_bounds__(256) void gat_agg1(const int* __restrict__ rowptr,
                                                const unsigned* __restrict__ csru,
                                                const float* __restrict__ aS,
                                                const float* __restrict__ aD,
                                                const unsigned char* __restrict__ h1f8,
                                                unsigned short* __restrict__ out1b) {
    const int wid = threadIdx.x >> 6, lane = threadIdx.x & 63;
    const int grp = lane >> 5, li = lane & 31;
    const int d = (blockIdx.x * 4 + wid) * 2 + grp;   // 6250 blocks * 8 = 50000 exact
    const int st = rowptr[d], en = rowptr[d + 1];
    const float2 ad_ = *(const float2*)(aD + 2 * (size_t)d);
    const int coff = li << 3;              // 8 fp8 channels per lane (byte offset)
    const int sh = (li < 16) ? 16 : 0;     // head0 lanes take e0 (low), head1 take e1
    float a0 = 0.f, a1 = 0.f, a2 = 0.f, a3 = 0.f;
    float a4 = 0.f, a5 = 0.f, a6 = 0.f, a7 = 0.f;
    float sd0 = 0.f, sd1 = 0.f;
    for (int b = st; b < en; b += 32) {
        int i = b + li;
        int s = 0; unsigned pk = 0;
        if (i < en) {
            s = (int)(csru[i] & 0xffffu);
            float2 as_ = *(const float2*)(aS + 2 * (size_t)s);
            float e0 = __expf(lrelu02(as_.x + ad_.x));
            float e1 = __expf(lrelu02(as_.y + ad_.y));
            sd0 += e0; sd1 += e1;
            pk = ((unsigned)f2bf(e1) << 16) | (unsigned)f2bf(e0);
        }
        int cnt = min(32, en - b);
        int k = 0;
        for (; k + 7 < cnt; k += 8) {
            int ss0 = __shfl(s, k, 32),     ss1 = __shfl(s, k + 1, 32);
            int ss2 = __shfl(s, k + 2, 32), ss3 = __shfl(s, k + 3, 32);
            int ss4 = __shfl(s, k + 4, 32), ss5 = __shfl(s, k + 5, 32);
            int ss6 = __shfl(s, k + 6, 32), ss7 = __shfl(s, k + 7, 32);
            unsigned p0 = (unsigned)__shfl((int)pk, k, 32);
            unsigned p1 = (unsigned)__shfl((int)pk, k + 1, 32);
            unsigned p2 = (unsigned)__shfl((int)pk, k + 2, 32);
            unsigned p3 = (unsigned)__shfl((int)pk, k + 3, 32);
            unsigned p4 = (unsigned)__shfl((int)pk, k + 4, 32);
            unsigned p5 = (unsigned)__shfl((int)pk, k + 5, 32);
            unsigned p6 = (unsigned)__shfl((int)pk, k + 6, 32);
            unsigned p7 = (unsigned)__shfl((int)pk, k + 7, 32);
            uint2 u0 = *(const uint2*)(h1f8 + (size_t)ss0 * C1 + coff);
            uint2 u1 = *(const uint2*)(h1f8 + (size_t)ss1 * C1 + coff);
            uint2 u2 = *(const uint2*)(h1f8 + (size_t)ss2 * C1 + coff);
            uint2 u3 = *(const uint2*)(h1f8 + (size_t)ss3 * C1 + coff);
            uint2 u4 = *(const uint2*)(h1f8 + (size_t)ss4 * C1 + coff);
            uint2 u5 = *(const uint2*)(h1f8 + (size_t)ss5 * C1 + coff);
            uint2 u6 = *(const uint2*)(h1f8 + (size_t)ss6 * C1 + coff);
            uint2 u7 = *(const uint2*)(h1f8 + (size_t)ss7 * C1 + coff);
            float al0 = __uint_as_float((p0 << sh) & 0xffff0000u);
            float al1 = __uint_as_float((p1 << sh) & 0xffff0000u);
            float al2 = __uint_as_float((p2 << sh) & 0xffff0000u);
            float al3 = __uint_as_float((p3 << sh) & 0xffff0000u);
            float al4 = __uint_as_float((p4 << sh) & 0xffff0000u);
            float al5 = __uint_as_float((p5 << sh) & 0xffff0000u);
            float al6 = __uint_as_float((p6 << sh) & 0xffff0000u);
            float al7 = __uint_as_float((p7 << sh) & 0xffff0000u);
            float4 w0, w1;
            w0 = fp8x4(u0.x); w1 = fp8x4(u0.y);
            a0 = fmaf(w0.x, al0, a0); a1 = fmaf(w0.y, al0, a1);
            a2 = fmaf(w0.z, al0, a2); a3 = fmaf(w0.w, al0, a3);
            a4 = fmaf(w1.x, al0, a4); a5 = fmaf(w1.y, al0, a5);
            a6 = fmaf(w1.z, al0, a6); a7 = fmaf(w1.w, al0, a7);
            w0 = fp8x4(u1.x); w1 = fp8x4(u1.y);
            a0 = fmaf(w0.x, al1, a0); a1 = fmaf(w0.y, al1, a1);
            a2 = fmaf(w0.z, al1, a2); a3 = fmaf(w0.w, al1, a3);
            a4 = fmaf(w1.x, al1, a4); a5 = fmaf(w1.y, al1, a5);
            a6 = fmaf(w1.z, al1, a6); a7 = fmaf(w1.w, al1, a7);
            w0 = fp8x4(u2.x); w1 = fp8x4(u2.y);
            a0 = fmaf(w0.x, al2, a0); a1 = fmaf(w0.y, al2, a1);
            a2 = fmaf(w0.z, al2, a2); a3 = fmaf(w0.w, al2, a3);
            a4 = fmaf(w1.x, al2, a4); a5 = fmaf(w1.y, al2, a5);
            a6 = fmaf(w1.z, al2, a6); a7 = fmaf(w1.w, al2, a7);
            w0 = fp8x4(u3.x); w1 = fp8x4(u3.y);
            a0 = fmaf(w0.x, al3, a0); a1 = fmaf(w0.y, al3, a1);
            a2 = fmaf(w0.z, al3, a2); a3 = fmaf(w0.w, al3, a3);
            a4 = fmaf(w1.x, al3, a4); a5 = fmaf(w1.y, al3, a5);
            a6 = fmaf(w1.z, al3, a6); a7 = fmaf(w1.w, al3, a7);
            w0 = fp8x4(u4.x); w1 = fp8x4(u4.y);
            a0 = fmaf(w0.x, al4, a0); a1 = fmaf(w0.y, al4, a1);
            a2 = fmaf(w0.z, al4, a2); a3 = fmaf(w0.w, al4, a3);
            a4 = fmaf(w1.x, al4, a4); a5 = fmaf(w1.y, al4, a5);
            a6 = fmaf(w1.z, al4, a6); a7 = fmaf(w1.w, al4, a7);
            w0 = fp8x4(u5.x); w1 = fp8x4(u5.y);
            a0 = fmaf(w0.x, al5, a0); a1 = fmaf(w0.y, al5, a1);
            a2 = fmaf(w0.z, al5, a2); a3 = fmaf(w0.w, al5, a3);
            a4 = fmaf(w1.x, al5, a4); a5 = fmaf(w1.y, al5, a5);
            a6 = fmaf(w1.z, al5, a6); a7 = fmaf(w1.w, al5, a7);
            w0 = fp8x4(u6.x); w1 = fp8x4(u6.y);
            a0 = fmaf(w0.x, al6, a0); a1 = fmaf(w0.y, al6, a1);
            a2 = fmaf(w0.z, al6, a2); a3 = fmaf(w0.w, al6, a3);
            a4 = fmaf(w1.x, al6, a4); a5 = fmaf(w1.y, al6, a5);
            a6 = fmaf(w1.z, al6, a6); a7 = fmaf(w1.w, al6, a7);
            w0 = fp8x4(u7.x); w1 = fp8x4(u7.y);
            a0 = fmaf(w0.x, al7, a0); a1 = fmaf(w0.y, al7, a1);
            a2 = fmaf(w0.z, al7, a2); a3 = fmaf(w0.w, al7, a3);
            a4 = fmaf(w1.x, al7, a4); a5 = fmaf(w1.y, al7, a5);
            a6 = fmaf(w1.z, al7, a6); a7 = fmaf(w1.w, al7, a7);
        }
        for (; k < cnt; ++k) {
            int ss = __shfl(s, k, 32);
            unsigned p = (unsigned)__shfl((int)pk, k, 32);
            float al = __uint_as_float((p << sh) & 0xffff0000u);
            uint2 u = *(const uint2*)(h1f8 + (size_t)ss * C1 + coff);
            float4 w0 = fp8x4(u.x), w1 = fp8x4(u.y);
            a0 = fmaf(w0.x, al, a0); a1 = fmaf(w0.y, al, a1);
            a2 = fmaf(w0.z, al, a2); a3 = fmaf(w0.w, al, a3);
            a4 = fmaf(w1.x, al, a4); a5 = fmaf(w1.y, al, a5);
            a6 = fmaf(w1.z, al, a6); a7 = fmaf(w1.w, al, a7);
        }
    }
    // reduce denominators over the 32-lane group (xor masks <32 stay in group)
#pragma unroll
    for (int o = 1; o < 32; o <<= 1) {
        sd0 += __shfl_xor(sd0, o, 64);
        sd1 += __shfl_xor(sd1, o, 64);
    }
    float inv = (li < 16) ? 1.f / (sd0 + 1e-16f) : 1.f / (sd1 + 1e-16f);
    ushort4 o0, o1;
    o0.x = f2bf(a0 * inv); o0.y = f2bf(a1 * inv);
    o0.z = f2bf(a2 * inv); o0.w = f2bf(a3 * inv);
    o1.x = f2bf(a4 * inv); o1.y = f2bf(a5 * inv);
    o1.z = f2bf(a6 * inv); o1.w = f2bf(a7 * inv);
    *(ushort4*)(out1b + (size_t)d * C1 + coff) = o0;
    *(ushort4*)(out1b + (size_t)d * C1 + coff + 4) = o1;
}

// ------- aggregation layer 2: 1 dst/WAVE, 4 edge-quadrants x 16 channel-lanes,
//         self-contained records, 16 edges in flight (4/quadrant); 2 shfl_xor
//         reductions at the end; pooling merges 4 dsts -> 1 atomic/channel. -------
__global__ __launch_bounds__(256) void gat_agg2(const int* __restrict__ rowptr,
                                                const float2* __restrict__ eb2,
                                                const unsigned char* __restrict__ h2f8,
                                                const int* __restrict__ batch,
                                                const float* __restrict__ b2,
                                                float* __restrict__ sums) {
    __shared__ float pool[4][64];
    const int wid = threadIdx.x >> 6, lane = threadIdx.x & 63;
    const int eq = lane >> 4;              // edge quadrant 0..3
    const int li = lane & 15;              // channel lane
    const int c = li << 2;                 // 4 channels per lane (byte offset)
    const int d = blockIdx.x * 4 + wid;    // 12500 blocks * 4 = 50000 exact
    const int st = rowptr[d], en = rowptr[d + 1];
    float a0 = 0.f, a1 = 0.f, a2 = 0.f, a3 = 0.f;
    float sd = 0.f;
    const int en1 = en - 1;
    for (int i = st; i < en; i += 16) {
        int j0 = i + eq, j1 = j0 + 4, j2 = j0 + 8, j3 = j0 + 12;
        int c0 = min(j0, en1), c1 = min(j1, en1), c2 = min(j2, en1), c3 = min(j3, en1);
        float2 q0 = eb2[c0], q1 = eb2[c1], q2 = eb2[c2], q3 = eb2[c3];
        unsigned v0 = *(const unsigned*)(h2f8 + (size_t)__float_as_uint(q0.y) + c);
        unsigned v1 = *(const unsigned*)(h2f8 + (size_t)__float_as_uint(q1.y) + c);
        unsigned v2 = *(const unsigned*)(h2f8 + (size_t)__float_as_uint(q2.y) + c);
        unsigned v3 = *(const unsigned*)(h2f8 + (size_t)__float_as_uint(q3.y) + c);
        float m0 = (j0 <= en1) ? q0.x : 0.f;
        float m1 = (j1 <= en1) ? q1.x : 0.f;
        float m2 = (j2 <= en1) ? q2.x : 0.f;
        float m3 = (j3 <= en1) ? q3.x : 0.f;
        sd += (m0 + m1) + (m2 + m3);
        float4 w;
        w = fp8x4(v0);
        a0 = fmaf(w.x, m0, a0); a1 = fmaf(w.y, m0, a1);
        a2 = fmaf(w.z, m0, a2); a3 = fmaf(w.w, m0, a3);
        w = fp8x4(v1);
        a0 = fmaf(w.x, m1, a0); a1 = fmaf(w.y, m1, a1);
        a2 = fmaf(w.z, m1, a2); a3 = fmaf(w.w, m1, a3);
        w = fp8x4(v2);
        a0 = fmaf(w.x, m2, a0); a1 = fmaf(w.y, m2, a1);
        a2 = fmaf(w.z, m2, a2); a3 = fmaf(w.w, m2, a3);
        w = fp8x4(v3);
        a0 = fmaf(w.x, m3, a0); a1 = fmaf(w.y, m3, a1);
        a2 = fmaf(w.z, m3, a2); a3 = fmaf(w.w, m3, a3);
    }
    // reduce over the 4 edge-quadrants (lanes ^16, ^32 share channels)
    a0 += __shfl_xor(a0, 16, 64); a0 += __shfl_xor(a0, 32, 64);
    a1 += __shfl_xor(a1, 16, 64); a1 += __shfl_xor(a1, 32, 64);
    a2 += __shfl_xor(a2, 16, 64); a2 += __shfl_xor(a2, 32, 64);
    a3 += __shfl_xor(a3, 16, 64); a3 += __shfl_xor(a3, 32, 64);
    sd += __shfl_xor(sd, 16, 64); sd += __shfl_xor(sd, 32, 64);
    float inv = 1.f / (sd + 1e-16f);
    if (eq == 0)
        *(float4*)&pool[wid][c] = make_float4(a0 * inv, a1 * inv, a2 * inv, a3 * inv);
    __syncthreads();
    const int slot = blockIdx.x & (NSLOT - 1);
    const int d0 = blockIdx.x * 4;
    int g0 = batch[d0], g3 = batch[d0 + 3];
    if (g0 == g3) {                        // common case (sorted batch): 1 atomic/channel
        if (threadIdx.x < 64) {
            int ch = threadIdx.x;
            float bb_ = b2[ch];
            float v = 0.f;
#pragma unroll
            for (int r = 0; r < 4; ++r) {
                float t = pool[r][ch] + bb_;
                v += (t > 0.f) ? t : expm1f(t);
            }
            unsafeAtomicAdd(sums + ((size_t)slot * NG + g0) * O2 + ch, v);
        }
    } else {                               // graph boundary inside block (rare)
        int r = threadIdx.x >> 6, ch = threadIdx.x & 63;
        float t = pool[r][ch] + b2[ch];
        t = (t > 0.f) ? t : expm1f(t);
        unsafeAtomicAdd(sums + ((size_t)slot * NG + batch[d0 + r]) * O2 + ch, t);
    }
}

// ------- classifier: reduce slots, mean, @Wc + bc -------
__global__ __launch_bounds__(64) void gat_cls(const float* __restrict__ sums,
                                              const int* __restrict__ bnds,
                                              const float* __restrict__ Wc,
                                              const float* __restrict__ bc,
                                              float* __restrict__ out) {
    int g = blockIdx.x, c = threadIdx.x;
    float s = 0.f;
#pragma unroll
    for (int sl = 0; sl < NSLOT; ++sl)
        s += sums[((size_t)sl * NG + g) * O2 + c];
    float cnt = (float)(bnds[g + 1] - bnds[g]);
    float p = s / fmaxf(cnt, 1.f);
    float p0 = p * Wc[c * 2 + 0];
    float p1 = p * Wc[c * 2 + 1];
#pragma unroll
    for (int off = 1; off < 64; off <<= 1) {
        p0 += __shfl_xor(p0, off, 64);
        p1 += __shfl_xor(p1, off, 64);
    }
    if (c == 0) {
        out[g * 2 + 0] = p0 + bc[0];
        out[g * 2 + 1] = p1 + bc[1];
    }
}

extern "C" void kernel_launch(void* const* d_in, const int* in_sizes, int n_in,
                              void* d_out, int out_size, void* d_ws, size_t ws_size,
                              hipStream_t stream) {
    const float* x   = (const float*)d_in[0];
    const int*   ei  = (const int*)d_in[1];
    const int*   bat = (const int*)d_in[2];
    const float* W1  = (const float*)d_in[3];
    const float* as1 = (const float*)d_in[4];
    const float* ad1 = (const float*)d_in[5];
    const float* b1  = (const float*)d_in[6];
    const float* W2  = (const float*)d_in[7];
    const float* as2 = (const float*)d_in[8];
    const float* ad2 = (const float*)d_in[9];
    const float* b2  = (const float*)d_in[10];
    const float* Wc  = (const float*)d_in[11];
    const float* bc  = (const float*)d_in[12];
    float* out = (float*)d_out;

    char* ws = (char*)d_ws;
    size_t off = 0;
    auto alloc = [&](size_t b) { char* p = ws + off; off += (b + 255) & ~(size_t)255; return p; };
    // bh (256 w) | gcur (256 w)  -- zeroed by gat_zero (1 block)
    int* bh   = (int*)alloc(512 * 4);
    int* gcur = bh + 256;
    // sums -- zeroed by binA's extra blocks
    float* sums = (float*)alloc((size_t)SUMW * 4);

    unsigned char*  h1f8  = (unsigned char*)alloc((size_t)NN * C1);
    unsigned short* out1b = (unsigned short*)alloc((size_t)NN * C1 * 2);
    unsigned char*  h2f8  = (unsigned char*)alloc((size_t)NN * O2);
    unsigned short* w1t   = (unsigned short*)alloc((size_t)C1 * INC * 2);
    unsigned short* w2t   = (unsigned short*)alloc((size_t)O2 * C1 * 2);
    float* aS1    = (float*)alloc((size_t)NN * 2 * 4);
    float* aD1    = (float*)alloc((size_t)NN * 2 * 4);
    float* aS2    = (float*)alloc((size_t)NN * 4);
    float* aD2    = (float*)alloc((size_t)NN * 4);
    int*   rowptr = (int*)alloc((size_t)(NN + 1) * 4);
    int*   bb     = (int*)alloc(256 * 4);
    unsigned* csru = (unsigned*)alloc((size_t)NE * 4);
    unsigned* ebuf = (unsigned*)alloc((size_t)NE * 4);
    float2* eb2   = (float2*)alloc((size_t)NE * 8);
    int*   bnds   = (int*)alloc(65 * 4);
    if (off > ws_size) return;

    // --- zero bh|gcur (tiny) ---
    gat_zero<<<1, 128, 0, stream>>>((float4*)bh);

    // --- fused prep: 196-bucket histogram | W transpose + bounds ---
    gat_prep<<<PB_HB + PB_W, 256, 0, stream>>>(ei, W1, W2, bat, bh, w1t, w2t, bnds);

    // --- bucket bases + counting sort (binA also zeroes sums) ---
    gat_scanb<<<1, 256, 0, stream>>>(bh, bb);
    gat_binA<<<NBA + SUMQ / 256, 256, 0, stream>>>(ei, bb, gcur, ebuf, (float4*)sums);
    gat_binB_gemm1<<<NBKT + (NN + 63) / 64, 256, 0, stream>>>(ebuf, bb, rowptr, csru,
                                                              x, w1t, as1, ad1,
                                                              h1f8, aS1, aD1);

    // --- layer 1 aggregation (r0 structure: 2 dsts/wave, shuffle-broadcast e) ---
    gat_agg1<<<NN / 8, 256, 0, stream>>>(rowptr, csru, aS1, aD1, h1f8, out1b);

    // --- layer 2 gemm + att2 ---
    gat_gemm2<<<(NN + 63) / 64, 256, 0, stream>>>(out1b, b1, w2t, as2, ad2,
                                                  h2f8, aS2, aD2);

    // --- per-edge records, layer 2 (streaming) ---
    gat_e2<<<NE / 256, 256, 0, stream>>>(csru, aS2, aD2, eb2);

    // --- layer 2 aggregation + fused pooling ---
    gat_agg2<<<NN / 4, 256, 0, stream>>>(rowptr, eb2, h2f8, bat, b2, sums);

    // --- classify ---
    gat_cls<<<NG, 64, 0, stream>>>(sums, bnds, Wc, bc, out);
}